// Round 3
// baseline (246.100 us; speedup 1.0000x reference)
//
#include <hip/hip_runtime.h>
#include <hip/hip_bf16.h>
#include <stdint.h>

typedef __bf16 bf16x8 __attribute__((ext_vector_type(8)));
typedef float  f32x4  __attribute__((ext_vector_type(4)));

typedef __attribute__((address_space(1))) void gas1_t;
typedef __attribute__((address_space(3))) void as3_t;

__device__ __forceinline__ void gload_lds16(const void* g, void* l) {
  // width=16 global->LDS DMA; LDS dest is wave-uniform base + lane*16
  __builtin_amdgcn_global_load_lds((gas1_t*)g, (as3_t*)l, 16, 0, 0);
}

__device__ __forceinline__ f32x4 zero4() { f32x4 z = {0.f, 0.f, 0.f, 0.f}; return z; }

// ---------------- transpose + cast: W[K][N] f32 -> WT[N][K] bf16 ----------------
__global__ void transpose_cast(const float* __restrict__ W, __bf16* __restrict__ WT,
                               int K, int N) {
  __shared__ float tile[32][33];
  const int n0 = blockIdx.x * 32, k0 = blockIdx.y * 32;
  const int tx = threadIdx.x, ty = threadIdx.y;
  for (int i = ty; i < 32; i += 8) tile[i][tx] = W[(size_t)(k0 + i) * N + n0 + tx];
  __syncthreads();
  for (int i = ty; i < 32; i += 8) WT[(size_t)(n0 + i) * K + k0 + tx] = (__bf16)tile[tx][i];
}

// ---------------- GEMM: C[M][N] = A[M][K] @ BT[N][K]^T + bias ----------------
// 128x128 tile, BK=32, 4 waves (2x2), each wave 64x64 = 4x4 subtiles of 16x16.
// A_F32: A is f32, reg-staged with on-the-fly bf16 convert. Else bf16 via global_load_lds.
template <int OUT_BF16, int A_F32>
__global__ __launch_bounds__(256) void gemm_bt(const void* __restrict__ Ap,
                                               const __bf16* __restrict__ BT,
                                               const float* __restrict__ bias,
                                               void* __restrict__ Cout,
                                               int M, int N, int K) {
  __shared__ __bf16 As[2][4096];  // [128][32] bf16, linear
  __shared__ __bf16 Bs[2][4096];
  const int tid = threadIdx.x;
  const int lane = tid & 63, w = tid >> 6;
  const int wr = w >> 1, wc = w & 1;
  const int lgrp = lane >> 4, lcol = lane & 15;
  const int m0 = blockIdx.y * 128, n0 = blockIdx.x * 128;

  f32x4 acc[4][4];
#pragma unroll
  for (int m = 0; m < 4; ++m)
#pragma unroll
    for (int n = 0; n < 4; ++n) acc[m][n] = zero4();

  const int nk = K >> 5;

  auto stageB = [&](int buf, int k0) {
#pragma unroll
    for (int q = 0; q < 2; ++q) {
      const int c = q * 256 + w * 64 + lane;  // 16B chunk id, 512 per tile
      const int row = c >> 2, kc = (c & 3) * 8;
      const int ldsoff = (q * 256 + w * 64) * 16;  // wave-uniform
      gload_lds16(BT + (size_t)(n0 + row) * K + k0 + kc, (char*)&Bs[buf][0] + ldsoff);
    }
  };
  auto stageA = [&](int buf, int k0) {
    if (A_F32) {
      const float* A = (const float*)Ap;
      const int c0 = tid * 2;               // two consecutive 8-elem chunks
      const int row = c0 >> 2, kc = (c0 & 3) * 8;
      const float* src = A + (size_t)(m0 + row) * K + k0 + kc;
      const f32x4 v0 = *(const f32x4*)(src);
      const f32x4 v1 = *(const f32x4*)(src + 4);
      const f32x4 v2 = *(const f32x4*)(src + 8);
      const f32x4 v3 = *(const f32x4*)(src + 12);
      bf16x8 o0, o1;
#pragma unroll
      for (int j = 0; j < 4; ++j) {
        o0[j] = (__bf16)v0[j]; o0[j + 4] = (__bf16)v1[j];
        o1[j] = (__bf16)v2[j]; o1[j + 4] = (__bf16)v3[j];
      }
      *(bf16x8*)((char*)&As[buf][0] + c0 * 16) = o0;
      *(bf16x8*)((char*)&As[buf][0] + c0 * 16 + 16) = o1;
    } else {
      const __bf16* A = (const __bf16*)Ap;
#pragma unroll
      for (int q = 0; q < 2; ++q) {
        const int c = q * 256 + w * 64 + lane;
        const int row = c >> 2, kc = (c & 3) * 8;
        const int ldsoff = (q * 256 + w * 64) * 16;
        gload_lds16(A + (size_t)(m0 + row) * K + k0 + kc, (char*)&As[buf][0] + ldsoff);
      }
    }
  };

  stageA(0, 0);
  stageB(0, 0);
  __syncthreads();
  int cur = 0;
  for (int t = 0; t < nk; ++t) {
    if (t + 1 < nk) { stageA(cur ^ 1, (t + 1) * 32); stageB(cur ^ 1, (t + 1) * 32); }
    bf16x8 af[4], bfr[4];
#pragma unroll
    for (int m = 0; m < 4; ++m)
      af[m] = *(const bf16x8*)&As[cur][(wr * 64 + m * 16 + lcol) * 32 + lgrp * 8];
#pragma unroll
    for (int n = 0; n < 4; ++n)
      bfr[n] = *(const bf16x8*)&Bs[cur][(wc * 64 + n * 16 + lcol) * 32 + lgrp * 8];
#pragma unroll
    for (int m = 0; m < 4; ++m)
#pragma unroll
      for (int n = 0; n < 4; ++n)
        acc[m][n] = __builtin_amdgcn_mfma_f32_16x16x32_bf16(af[m], bfr[n], acc[m][n], 0, 0, 0);
    __syncthreads();  // drains vmcnt (DMA staged) + lgkmcnt (reads/writes done)
    cur ^= 1;
  }

#pragma unroll
  for (int m = 0; m < 4; ++m) {
#pragma unroll
    for (int n = 0; n < 4; ++n) {
      const int col = n0 + wc * 64 + n * 16 + lcol;
      const float bv = bias[col];
#pragma unroll
      for (int r = 0; r < 4; ++r) {
        const int row = m0 + wr * 64 + m * 16 + lgrp * 4 + r;
        const float v = acc[m][n][r] + bv;
        if (OUT_BF16)
          ((__bf16*)Cout)[(size_t)row * N + col] = (__bf16)v;
        else
          ((float*)Cout)[(size_t)row * N + col] = v;
      }
    }
  }
}

// ---------------- fused causal flash attention ----------------
// grid (T/64, B*H); 4 waves; wave w owns q-rows [qb+16w, qb+16w+16), KV block = 64.
// qkv: bf16 [B*T][3072]; q at col h*64, k at 1024+h*64, v at 2048+h*64.
__global__ __launch_bounds__(256) void attn_fused(const __bf16* __restrict__ qkv,
                                                  __bf16* __restrict__ attnb) {
  __shared__ __bf16 Kl[64][80];       // K tile row-major [kv][d], pad->4-way
  __shared__ __bf16 Vt[64][80];       // V^T tile [d][kv]
  __shared__ __bf16 Pl[4][16][80];    // per-wave P [q][kv]
  const int tid = threadIdx.x, lane = tid & 63, w = tid >> 6;
  const int lgrp = lane >> 4, lcol = lane & 15;
  const int qt = blockIdx.x, bh = blockIdx.y;
  const int b = bh >> 4, h = bh & 15;
  const int qb = qt * 64;
  const __bf16* base = qkv + (size_t)b * 2048 * 3072;

  // Q fragment (A-operand): row = lane&15, k(d) = (lane>>4)*8 + j (+32 per slice)
  const int qrow = qb + w * 16 + lcol;
  const __bf16* qptr = base + (size_t)qrow * 3072 + h * 64;
  const bf16x8 qf0 = *(const bf16x8*)(qptr + lgrp * 8);
  const bf16x8 qf1 = *(const bf16x8*)(qptr + 32 + lgrp * 8);

  float m_r[4], l_r[4];
  f32x4 acc_o[4];
#pragma unroll
  for (int r = 0; r < 4; ++r) { m_r[r] = -1e30f; l_r[r] = 0.f; }
#pragma unroll
  for (int d = 0; d < 4; ++d) acc_o[d] = zero4();

  const int nkv = qt + 1;
  for (int kvb = 0; kvb < nkv; ++kvb) {
    const int kv0 = kvb * 64;
    __syncthreads();  // previous iteration's Kl/Vt reads complete
#pragma unroll
    for (int p = 0; p < 2; ++p) {
      const int idx = p * 256 + tid;
      const int kvr = idx >> 3, d0 = (idx & 7) * 8;
      const __bf16* kp = base + (size_t)(kv0 + kvr) * 3072 + 1024 + h * 64 + d0;
      *(bf16x8*)&Kl[kvr][d0] = *(const bf16x8*)kp;
      const bf16x8 vv = *(const bf16x8*)(kp + 1024);
#pragma unroll
      for (int j = 0; j < 8; ++j) Vt[d0 + j][kvr] = vv[j];
    }
    __syncthreads();

    // S = Q @ K^T : B-operand col = kv = lane&15, k(d) contiguous
    f32x4 accs[4];
#pragma unroll
    for (int sub = 0; sub < 4; ++sub) {
      accs[sub] = zero4();
#pragma unroll
      for (int s = 0; s < 2; ++s) {
        const bf16x8 kb = *(const bf16x8*)&Kl[sub * 16 + lcol][s * 32 + lgrp * 8];
        accs[sub] = __builtin_amdgcn_mfma_f32_16x16x32_bf16(s ? qf1 : qf0, kb, accs[sub], 0, 0, 0);
      }
    }

    // scale + causal mask (D layout: col=lane&15 -> kv, row=4*(lane>>4)+r -> q)
    float sv[4][4];
    const int qg = qb + w * 16 + lgrp * 4;
#pragma unroll
    for (int sub = 0; sub < 4; ++sub) {
      const int kvg = kv0 + sub * 16 + lcol;
#pragma unroll
      for (int r = 0; r < 4; ++r)
        sv[sub][r] = (kvg <= qg + r) ? accs[sub][r] * 0.125f : -1e30f;
    }

    // wave-parallel online softmax (16-lane-group reduction)
#pragma unroll
    for (int r = 0; r < 4; ++r) {
      float rm = fmaxf(fmaxf(sv[0][r], sv[1][r]), fmaxf(sv[2][r], sv[3][r]));
      rm = fmaxf(rm, __shfl_xor(rm, 1));
      rm = fmaxf(rm, __shfl_xor(rm, 2));
      rm = fmaxf(rm, __shfl_xor(rm, 4));
      rm = fmaxf(rm, __shfl_xor(rm, 8));
      const float nm = fmaxf(m_r[r], rm);
      const float sf = __expf(m_r[r] - nm);
      m_r[r] = nm;
      float rs = 0.f;
#pragma unroll
      for (int sub = 0; sub < 4; ++sub) {
        const float pv = __expf(sv[sub][r] - nm);
        sv[sub][r] = pv;
        rs += pv;
      }
      rs += __shfl_xor(rs, 1);
      rs += __shfl_xor(rs, 2);
      rs += __shfl_xor(rs, 4);
      rs += __shfl_xor(rs, 8);
      l_r[r] = l_r[r] * sf + rs;
#pragma unroll
      for (int d = 0; d < 4; ++d) acc_o[d][r] *= sf;
    }

    // P -> LDS (layout change D-layout -> A-layout), per-wave private buffer
#pragma unroll
    for (int sub = 0; sub < 4; ++sub)
#pragma unroll
      for (int r = 0; r < 4; ++r)
        Pl[w][lgrp * 4 + r][sub * 16 + lcol] = (__bf16)sv[sub][r];
    asm volatile("s_waitcnt lgkmcnt(0)" ::: "memory");
    __builtin_amdgcn_sched_barrier(0);  // rule 18: pin reads after the waitcnt

    // O += P @ V
#pragma unroll
    for (int s = 0; s < 2; ++s) {
      const bf16x8 pf = *(const bf16x8*)&Pl[w][lcol][s * 32 + lgrp * 8];
#pragma unroll
      for (int d = 0; d < 4; ++d) {
        const bf16x8 vf = *(const bf16x8*)&Vt[d * 16 + lcol][s * 32 + lgrp * 8];
        acc_o[d] = __builtin_amdgcn_mfma_f32_16x16x32_bf16(pf, vf, acc_o[d], 0, 0, 0);
      }
    }
  }

  // epilogue: O / l, write bf16 [B*T][1024] (= [B,T,H,D] flattened)
#pragma unroll
  for (int d = 0; d < 4; ++d) {
#pragma unroll
    for (int r = 0; r < 4; ++r) {
      const int q = qb + w * 16 + lgrp * 4 + r;
      const int col = h * 64 + d * 16 + lcol;
      attnb[(size_t)(b * 2048 + q) * 1024 + col] = (__bf16)(acc_o[d][r] / l_r[r]);
    }
  }
}

extern "C" void kernel_launch(void* const* d_in, const int* in_sizes, int n_in,
                              void* d_out, int out_size, void* d_ws, size_t ws_size,
                              hipStream_t stream) {
  const float* x    = (const float*)d_in[0];
  const float* Wqkv = (const float*)d_in[1];
  const float* bqkv = (const float*)d_in[2];
  const float* Wout = (const float*)d_in[3];
  const float* bout = (const float*)d_in[4];
  float* out = (float*)d_out;

  // Workspace time-multiplexed, peak 32 MB:
  //   [0,24M)  qkvb  (bf16 [4096][3072])    -- dead after attn
  //   [24,30M) wqkvT (bf16 [3072][1024])    -- dead after GEMM1
  //   [24,32M) attnb (bf16 [4096][1024])    -- written by attn (over dead wqkvT)
  //   [0,2M)   woutT (bf16 [1024][1024])    -- transposed AFTER attn (over dead qkvb)
  char* ws = (char*)d_ws;
  __bf16* qkvb  = (__bf16*)(ws);
  __bf16* wqkvT = (__bf16*)(ws + (24u << 20));
  __bf16* attnb = (__bf16*)(ws + (24u << 20));
  __bf16* woutT = (__bf16*)(ws);

  transpose_cast<<<dim3(3072 / 32, 1024 / 32), dim3(32, 8), 0, stream>>>(Wqkv, wqkvT, 1024, 3072);

  gemm_bt<1, 1><<<dim3(3072 / 128, 4096 / 128), dim3(256), 0, stream>>>(
      (const void*)x, wqkvT, bqkv, (void*)qkvb, 4096, 3072, 1024);

  attn_fused<<<dim3(2048 / 64, 2 * 16), dim3(256), 0, stream>>>(qkvb, attnb);

  transpose_cast<<<dim3(1024 / 32, 1024 / 32), dim3(32, 8), 0, stream>>>(Wout, woutT, 1024, 1024);

  gemm_bt<0, 0><<<dim3(1024 / 128, 4096 / 128), dim3(256), 0, stream>>>(
      (const void*)attnb, woutT, bout, (void*)out, 4096, 1024, 1024);
}

// Round 4
// 161.733 us; speedup vs baseline: 1.5216x; 1.5216x over previous
//
#include <hip/hip_runtime.h>
#include <hip/hip_bf16.h>
#include <stdint.h>

typedef __bf16 bf16x8 __attribute__((ext_vector_type(8)));
typedef float  f32x4  __attribute__((ext_vector_type(4)));

typedef __attribute__((address_space(1))) void gas1_t;
typedef __attribute__((address_space(3))) void as3_t;

__device__ __forceinline__ void gload_lds16(const void* g, void* l) {
  // width=16 global->LDS DMA; LDS dest is wave-uniform base + lane*16
  __builtin_amdgcn_global_load_lds((gas1_t*)g, (as3_t*)l, 16, 0, 0);
}

__device__ __forceinline__ f32x4 zero4() { f32x4 z = {0.f, 0.f, 0.f, 0.f}; return z; }

// ---------------- transpose + cast: W[K][N] f32 -> WT[N][K] bf16 ----------------
__global__ void transpose_cast(const float* __restrict__ W, __bf16* __restrict__ WT,
                               int K, int N) {
  __shared__ float tile[32][33];
  const int n0 = blockIdx.x * 32, k0 = blockIdx.y * 32;
  const int tx = threadIdx.x, ty = threadIdx.y;
  for (int i = ty; i < 32; i += 8) tile[i][tx] = W[(size_t)(k0 + i) * N + n0 + tx];
  __syncthreads();
  for (int i = ty; i < 32; i += 8) WT[(size_t)(n0 + i) * K + k0 + tx] = (__bf16)tile[tx][i];
}

// ---------------- GEMM: C[M][N] = A[M][K] @ BT[N][K]^T + bias ----------------
// 128x128 tile, BK=32, 4 waves (2x2), each wave 64x64 = 4x4 subtiles of 16x16.
// A_F32: A is f32, reg-staged with on-the-fly bf16 convert. Else bf16 via global_load_lds.
template <int OUT_BF16, int A_F32>
__global__ __launch_bounds__(256) void gemm_bt(const void* __restrict__ Ap,
                                               const __bf16* __restrict__ BT,
                                               const float* __restrict__ bias,
                                               void* __restrict__ Cout,
                                               int M, int N, int K) {
  __shared__ __bf16 As[2][4096];  // [128][32] bf16, linear
  __shared__ __bf16 Bs[2][4096];
  const int tid = threadIdx.x;
  const int lane = tid & 63, w = tid >> 6;
  const int wr = w >> 1, wc = w & 1;
  const int lgrp = lane >> 4, lcol = lane & 15;
  const int m0 = blockIdx.y * 128, n0 = blockIdx.x * 128;

  f32x4 acc[4][4];
#pragma unroll
  for (int m = 0; m < 4; ++m)
#pragma unroll
    for (int n = 0; n < 4; ++n) acc[m][n] = zero4();

  const int nk = K >> 5;

  auto stageB = [&](int buf, int k0) {
#pragma unroll
    for (int q = 0; q < 2; ++q) {
      const int c = q * 256 + w * 64 + lane;  // 16B chunk id, 512 per tile
      const int row = c >> 2, kc = (c & 3) * 8;
      const int ldsoff = (q * 256 + w * 64) * 16;  // wave-uniform
      gload_lds16(BT + (size_t)(n0 + row) * K + k0 + kc, (char*)&Bs[buf][0] + ldsoff);
    }
  };
  auto stageA = [&](int buf, int k0) {
    if (A_F32) {
      const float* A = (const float*)Ap;
      const int c0 = tid * 2;               // two consecutive 8-elem chunks
      const int row = c0 >> 2, kc = (c0 & 3) * 8;
      const float* src = A + (size_t)(m0 + row) * K + k0 + kc;
      const f32x4 v0 = *(const f32x4*)(src);
      const f32x4 v1 = *(const f32x4*)(src + 4);
      const f32x4 v2 = *(const f32x4*)(src + 8);
      const f32x4 v3 = *(const f32x4*)(src + 12);
      bf16x8 o0, o1;
#pragma unroll
      for (int j = 0; j < 4; ++j) {
        o0[j] = (__bf16)v0[j]; o0[j + 4] = (__bf16)v1[j];
        o1[j] = (__bf16)v2[j]; o1[j + 4] = (__bf16)v3[j];
      }
      *(bf16x8*)((char*)&As[buf][0] + c0 * 16) = o0;
      *(bf16x8*)((char*)&As[buf][0] + c0 * 16 + 16) = o1;
    } else {
      const __bf16* A = (const __bf16*)Ap;
#pragma unroll
      for (int q = 0; q < 2; ++q) {
        const int c = q * 256 + w * 64 + lane;
        const int row = c >> 2, kc = (c & 3) * 8;
        const int ldsoff = (q * 256 + w * 64) * 16;
        gload_lds16(A + (size_t)(m0 + row) * K + k0 + kc, (char*)&As[buf][0] + ldsoff);
      }
    }
  };

  stageA(0, 0);
  stageB(0, 0);
  __syncthreads();
  int cur = 0;
  for (int t = 0; t < nk; ++t) {
    if (t + 1 < nk) { stageA(cur ^ 1, (t + 1) * 32); stageB(cur ^ 1, (t + 1) * 32); }
    bf16x8 af[4], bfr[4];
#pragma unroll
    for (int m = 0; m < 4; ++m)
      af[m] = *(const bf16x8*)&As[cur][(wr * 64 + m * 16 + lcol) * 32 + lgrp * 8];
#pragma unroll
    for (int n = 0; n < 4; ++n)
      bfr[n] = *(const bf16x8*)&Bs[cur][(wc * 64 + n * 16 + lcol) * 32 + lgrp * 8];
#pragma unroll
    for (int m = 0; m < 4; ++m)
#pragma unroll
      for (int n = 0; n < 4; ++n)
        acc[m][n] = __builtin_amdgcn_mfma_f32_16x16x32_bf16(af[m], bfr[n], acc[m][n], 0, 0, 0);
    __syncthreads();  // drains vmcnt (DMA staged) + lgkmcnt (reads/writes done)
    cur ^= 1;
  }

#pragma unroll
  for (int m = 0; m < 4; ++m) {
#pragma unroll
    for (int n = 0; n < 4; ++n) {
      const int col = n0 + wc * 64 + n * 16 + lcol;
      const float bv = bias[col];
#pragma unroll
      for (int r = 0; r < 4; ++r) {
        const int row = m0 + wr * 64 + m * 16 + lgrp * 4 + r;
        const float v = acc[m][n][r] + bv;
        if (OUT_BF16)
          ((__bf16*)Cout)[(size_t)row * N + col] = (__bf16)v;
        else
          ((float*)Cout)[(size_t)row * N + col] = v;
      }
    }
  }
}

// ---------------- fused causal flash attention (v2) ----------------
// Load-balanced: grid (16, B*H); block handles q-tiles {p, 31-p} -> constant
// 34 KV-iters per block. T14 async staging (reg prefetch of next K/V tile).
// XOR-swizzled Vt and Pl to kill the 8-way / 4-way store bank conflicts.
// qkv: bf16 [B*T][3072]; q at col h*64, k at 1024+h*64, v at 2048+h*64.
__global__ __launch_bounds__(256) void attn_fused(const __bf16* __restrict__ qkv,
                                                  __bf16* __restrict__ attnb) {
  __shared__ __bf16 Kl[64][80];       // K tile [kv][d] (vector stores, even banks)
  __shared__ __bf16 Vt[64][80];       // V^T tile [d][kv], colblk ^= (row>>3)&7
  __shared__ __bf16 Pl[4][16][80];    // per-wave P [q][kv], colblk ^= (row>>2)&3
  const int tid = threadIdx.x, lane = tid & 63, w = tid >> 6;
  const int lgrp = lane >> 4, lcol = lane & 15;
  const int pair = blockIdx.x, bh = blockIdx.y;
  const int b = bh >> 4, h = bh & 15;
  const __bf16* base = qkv + (size_t)b * 2048 * 3072;

  // staging geometry (per thread): rows kvr0 / kvr0+32, cols d00..d00+7
  const int kvr0 = tid >> 3, kvr1 = kvr0 + 32;
  const int d00 = (tid & 7) * 8;
  // swizzled V^T column for this thread's scatter (row>>3 == tid&7 for all 8 j)
  const int vcol0 = ((((kvr0 >> 3) ^ (tid & 7)) << 3) | (kvr0 & 7));
  const int vcol1 = ((((kvr1 >> 3) ^ (tid & 7)) << 3) | (kvr1 & 7));
  const __bf16* kvbase = base + 1024 + h * 64 + d00;

#pragma unroll 1
  for (int half = 0; half < 2; ++half) {
    const int qt = half ? (31 - pair) : pair;
    const int qb = qt * 64;

    // Q fragment (A-operand): row = lane&15, k(d) = (lane>>4)*8 + j (+32 per slice)
    const int qrow = qb + w * 16 + lcol;
    const __bf16* qptr = base + (size_t)qrow * 3072 + h * 64;
    const bf16x8 qf0 = *(const bf16x8*)(qptr + lgrp * 8);
    const bf16x8 qf1 = *(const bf16x8*)(qptr + 32 + lgrp * 8);

    float m_r[4], l_r[4];
    f32x4 acc_o[4];
#pragma unroll
    for (int r = 0; r < 4; ++r) { m_r[r] = -1e30f; l_r[r] = 0.f; }
#pragma unroll
    for (int d = 0; d < 4; ++d) acc_o[d] = zero4();

    const int nkv = qt + 1;

    // prefetch tile 0 into registers
    bf16x8 kA, kB, vA, vB;
    {
      const __bf16* p0 = kvbase + (size_t)kvr0 * 3072;
      const __bf16* p1 = kvbase + (size_t)kvr1 * 3072;
      kA = *(const bf16x8*)p0; vA = *(const bf16x8*)(p0 + 1024);
      kB = *(const bf16x8*)p1; vB = *(const bf16x8*)(p1 + 1024);
    }

    for (int kvb = 0; kvb < nkv; ++kvb) {
      const int kv0 = kvb * 64;
      __syncthreads();  // previous tile's LDS reads complete
      // registers -> LDS
      *(bf16x8*)&Kl[kvr0][d00] = kA;
      *(bf16x8*)&Kl[kvr1][d00] = kB;
#pragma unroll
      for (int j = 0; j < 8; ++j) {
        Vt[d00 + j][vcol0] = vA[j];
        Vt[d00 + j][vcol1] = vB[j];
      }
      __syncthreads();
      // issue next tile's global loads (latency hides under compute below)
      if (kvb + 1 < nkv) {
        const __bf16* p0 = kvbase + (size_t)(kv0 + 64 + kvr0) * 3072;
        const __bf16* p1 = kvbase + (size_t)(kv0 + 64 + kvr1) * 3072;
        kA = *(const bf16x8*)p0; vA = *(const bf16x8*)(p0 + 1024);
        kB = *(const bf16x8*)p1; vB = *(const bf16x8*)(p1 + 1024);
      }

      // S = Q @ K^T : B-operand col = kv = lane&15, k(d) contiguous
      f32x4 accs[4];
#pragma unroll
      for (int sub = 0; sub < 4; ++sub) {
        accs[sub] = zero4();
#pragma unroll
        for (int s = 0; s < 2; ++s) {
          const bf16x8 kb = *(const bf16x8*)&Kl[sub * 16 + lcol][s * 32 + lgrp * 8];
          accs[sub] = __builtin_amdgcn_mfma_f32_16x16x32_bf16(s ? qf1 : qf0, kb, accs[sub], 0, 0, 0);
        }
      }

      // scale + causal mask (D layout: col=lane&15 -> kv, row=4*(lane>>4)+r -> q)
      float sv[4][4];
      const int qg = qb + w * 16 + lgrp * 4;
#pragma unroll
      for (int sub = 0; sub < 4; ++sub) {
        const int kvg = kv0 + sub * 16 + lcol;
#pragma unroll
        for (int r = 0; r < 4; ++r)
          sv[sub][r] = (kvg <= qg + r) ? accs[sub][r] * 0.125f : -1e30f;
      }

      // wave-parallel online softmax (16-lane-group reduction)
#pragma unroll
      for (int r = 0; r < 4; ++r) {
        float rm = fmaxf(fmaxf(sv[0][r], sv[1][r]), fmaxf(sv[2][r], sv[3][r]));
        rm = fmaxf(rm, __shfl_xor(rm, 1));
        rm = fmaxf(rm, __shfl_xor(rm, 2));
        rm = fmaxf(rm, __shfl_xor(rm, 4));
        rm = fmaxf(rm, __shfl_xor(rm, 8));
        const float nm = fmaxf(m_r[r], rm);
        const float sf = __expf(m_r[r] - nm);
        m_r[r] = nm;
        float rs = 0.f;
#pragma unroll
        for (int sub = 0; sub < 4; ++sub) {
          const float pv = __expf(sv[sub][r] - nm);
          sv[sub][r] = pv;
          rs += pv;
        }
        rs += __shfl_xor(rs, 1);
        rs += __shfl_xor(rs, 2);
        rs += __shfl_xor(rs, 4);
        rs += __shfl_xor(rs, 8);
        l_r[r] = l_r[r] * sf + rs;
#pragma unroll
        for (int d = 0; d < 4; ++d) acc_o[d][r] *= sf;
      }

      // P -> LDS (D-layout -> A-layout), swizzled: colblk ^= (row>>2)&3
      // store row = lgrp*4+r -> key = lgrp; col = sub*16+lcol
#pragma unroll
      for (int sub = 0; sub < 4; ++sub) {
        const int pc = ((((sub * 2 + (lcol >> 3)) ^ lgrp) << 3) | (lcol & 7));
#pragma unroll
        for (int r = 0; r < 4; ++r)
          Pl[w][lgrp * 4 + r][pc] = (__bf16)sv[sub][r];
      }
      asm volatile("s_waitcnt lgkmcnt(0)" ::: "memory");
      __builtin_amdgcn_sched_barrier(0);  // rule 18: pin reads after the waitcnt

      // O += P @ V
#pragma unroll
      for (int s = 0; s < 2; ++s) {
        // A-frag read row = lcol -> key = (lcol>>2)&3, colblk = 4s+lgrp
        const bf16x8 pf = *(const bf16x8*)&Pl[w][lcol][((4 * s + lgrp) ^ ((lcol >> 2) & 3)) * 8];
#pragma unroll
        for (int d = 0; d < 4; ++d) {
          // B-frag read row = d*16+lcol -> key = (2d + (lcol>>3))&7, colblk = 4s+lgrp
          const bf16x8 vf = *(const bf16x8*)&Vt[d * 16 + lcol][((4 * s + lgrp) ^ ((2 * d + (lcol >> 3)) & 7)) * 8];
          acc_o[d] = __builtin_amdgcn_mfma_f32_16x16x32_bf16(pf, vf, acc_o[d], 0, 0, 0);
        }
      }
    }

    // epilogue: O / l, write bf16 [B*T][1024] (= [B,T,H,D] flattened)
#pragma unroll
    for (int d = 0; d < 4; ++d) {
#pragma unroll
      for (int r = 0; r < 4; ++r) {
        const int q = qb + w * 16 + lgrp * 4 + r;
        const int col = h * 64 + d * 16 + lcol;
        attnb[(size_t)(b * 2048 + q) * 1024 + col] = (__bf16)(acc_o[d][r] / l_r[r]);
      }
    }
  }
}

extern "C" void kernel_launch(void* const* d_in, const int* in_sizes, int n_in,
                              void* d_out, int out_size, void* d_ws, size_t ws_size,
                              hipStream_t stream) {
  const float* x    = (const float*)d_in[0];
  const float* Wqkv = (const float*)d_in[1];
  const float* bqkv = (const float*)d_in[2];
  const float* Wout = (const float*)d_in[3];
  const float* bout = (const float*)d_in[4];
  float* out = (float*)d_out;

  // Workspace time-multiplexed, peak 32 MB:
  //   [0,24M)  qkvb  (bf16 [4096][3072])    -- dead after attn
  //   [24,30M) wqkvT (bf16 [3072][1024])    -- dead after GEMM1
  //   [24,32M) attnb (bf16 [4096][1024])    -- written by attn (over dead wqkvT)
  //   [0,2M)   woutT (bf16 [1024][1024])    -- transposed AFTER attn (over dead qkvb)
  char* ws = (char*)d_ws;
  __bf16* qkvb  = (__bf16*)(ws);
  __bf16* wqkvT = (__bf16*)(ws + (24u << 20));
  __bf16* attnb = (__bf16*)(ws + (24u << 20));
  __bf16* woutT = (__bf16*)(ws);

  transpose_cast<<<dim3(3072 / 32, 1024 / 32), dim3(32, 8), 0, stream>>>(Wqkv, wqkvT, 1024, 3072);

  gemm_bt<1, 1><<<dim3(3072 / 128, 4096 / 128), dim3(256), 0, stream>>>(
      (const void*)x, wqkvT, bqkv, (void*)qkvb, 4096, 3072, 1024);

  attn_fused<<<dim3(16, 2 * 16), dim3(256), 0, stream>>>(qkvb, attnb);

  transpose_cast<<<dim3(1024 / 32, 1024 / 32), dim3(32, 8), 0, stream>>>(Wout, woutT, 1024, 1024);

  gemm_bt<0, 0><<<dim3(1024 / 128, 4096 / 128), dim3(256), 0, stream>>>(
      (const void*)attnb, woutT, bout, (void*)out, 4096, 1024, 1024);
}

// Round 5
// 159.043 us; speedup vs baseline: 1.5474x; 1.0169x over previous
//
#include <hip/hip_runtime.h>
#include <hip/hip_bf16.h>
#include <stdint.h>

typedef __bf16 bf16x8 __attribute__((ext_vector_type(8)));
typedef float  f32x4  __attribute__((ext_vector_type(4)));

typedef __attribute__((address_space(1))) void gas1_t;
typedef __attribute__((address_space(3))) void as3_t;

__device__ __forceinline__ void gload_lds16(const void* g, void* l) {
  // width=16 global->LDS DMA; LDS dest is wave-uniform base + lane*16
  __builtin_amdgcn_global_load_lds((gas1_t*)g, (as3_t*)l, 16, 0, 0);
}

__device__ __forceinline__ f32x4 zero4() { f32x4 z = {0.f, 0.f, 0.f, 0.f}; return z; }

// ---------------- transpose + cast: W[K][N] f32 -> WT[N][K] bf16 ----------------
__global__ void transpose_cast(const float* __restrict__ W, __bf16* __restrict__ WT,
                               int K, int N) {
  __shared__ float tile[32][33];
  const int n0 = blockIdx.x * 32, k0 = blockIdx.y * 32;
  const int tx = threadIdx.x, ty = threadIdx.y;
  for (int i = ty; i < 32; i += 8) tile[i][tx] = W[(size_t)(k0 + i) * N + n0 + tx];
  __syncthreads();
  for (int i = ty; i < 32; i += 8) WT[(size_t)(n0 + i) * K + k0 + tx] = (__bf16)tile[tx][i];
}

// ---------------- GEMM: C[M][N] = A[M][K] @ BT[N][K]^T + bias ----------------
// 128x128 tile, BK=32, 4 waves (2x2), each wave 64x64 = 4x4 subtiles of 16x16.
// A_F32: A is f32, reg-staged with on-the-fly bf16 convert. Else bf16 via global_load_lds.
template <int OUT_BF16, int A_F32>
__global__ __launch_bounds__(256) void gemm_bt(const void* __restrict__ Ap,
                                               const __bf16* __restrict__ BT,
                                               const float* __restrict__ bias,
                                               void* __restrict__ Cout,
                                               int M, int N, int K) {
  __shared__ __bf16 As[2][4096];  // [128][32] bf16, linear
  __shared__ __bf16 Bs[2][4096];
  const int tid = threadIdx.x;
  const int lane = tid & 63, w = tid >> 6;
  const int wr = w >> 1, wc = w & 1;
  const int lgrp = lane >> 4, lcol = lane & 15;
  const int m0 = blockIdx.y * 128, n0 = blockIdx.x * 128;

  f32x4 acc[4][4];
#pragma unroll
  for (int m = 0; m < 4; ++m)
#pragma unroll
    for (int n = 0; n < 4; ++n) acc[m][n] = zero4();

  const int nk = K >> 5;

  auto stageB = [&](int buf, int k0) {
#pragma unroll
    for (int q = 0; q < 2; ++q) {
      const int c = q * 256 + w * 64 + lane;  // 16B chunk id, 512 per tile
      const int row = c >> 2, kc = (c & 3) * 8;
      const int ldsoff = (q * 256 + w * 64) * 16;  // wave-uniform
      gload_lds16(BT + (size_t)(n0 + row) * K + k0 + kc, (char*)&Bs[buf][0] + ldsoff);
    }
  };
  auto stageA = [&](int buf, int k0) {
    if (A_F32) {
      const float* A = (const float*)Ap;
      const int c0 = tid * 2;               // two consecutive 8-elem chunks
      const int row = c0 >> 2, kc = (c0 & 3) * 8;
      const float* src = A + (size_t)(m0 + row) * K + k0 + kc;
      const f32x4 v0 = *(const f32x4*)(src);
      const f32x4 v1 = *(const f32x4*)(src + 4);
      const f32x4 v2 = *(const f32x4*)(src + 8);
      const f32x4 v3 = *(const f32x4*)(src + 12);
      bf16x8 o0, o1;
#pragma unroll
      for (int j = 0; j < 4; ++j) {
        o0[j] = (__bf16)v0[j]; o0[j + 4] = (__bf16)v1[j];
        o1[j] = (__bf16)v2[j]; o1[j + 4] = (__bf16)v3[j];
      }
      *(bf16x8*)((char*)&As[buf][0] + c0 * 16) = o0;
      *(bf16x8*)((char*)&As[buf][0] + c0 * 16 + 16) = o1;
    } else {
      const __bf16* A = (const __bf16*)Ap;
#pragma unroll
      for (int q = 0; q < 2; ++q) {
        const int c = q * 256 + w * 64 + lane;
        const int row = c >> 2, kc = (c & 3) * 8;
        const int ldsoff = (q * 256 + w * 64) * 16;
        gload_lds16(A + (size_t)(m0 + row) * K + k0 + kc, (char*)&As[buf][0] + ldsoff);
      }
    }
  };

  stageA(0, 0);
  stageB(0, 0);
  __syncthreads();
  int cur = 0;
  for (int t = 0; t < nk; ++t) {
    if (t + 1 < nk) { stageA(cur ^ 1, (t + 1) * 32); stageB(cur ^ 1, (t + 1) * 32); }
    bf16x8 af[4], bfr[4];
#pragma unroll
    for (int m = 0; m < 4; ++m)
      af[m] = *(const bf16x8*)&As[cur][(wr * 64 + m * 16 + lcol) * 32 + lgrp * 8];
#pragma unroll
    for (int n = 0; n < 4; ++n)
      bfr[n] = *(const bf16x8*)&Bs[cur][(wc * 64 + n * 16 + lcol) * 32 + lgrp * 8];
#pragma unroll
    for (int m = 0; m < 4; ++m)
#pragma unroll
      for (int n = 0; n < 4; ++n)
        acc[m][n] = __builtin_amdgcn_mfma_f32_16x16x32_bf16(af[m], bfr[n], acc[m][n], 0, 0, 0);
    __syncthreads();  // drains vmcnt (DMA staged) + lgkmcnt (reads/writes done)
    cur ^= 1;
  }

#pragma unroll
  for (int m = 0; m < 4; ++m) {
#pragma unroll
    for (int n = 0; n < 4; ++n) {
      const int col = n0 + wc * 64 + n * 16 + lcol;
      const float bv = bias[col];
#pragma unroll
      for (int r = 0; r < 4; ++r) {
        const int row = m0 + wr * 64 + m * 16 + lgrp * 4 + r;
        const float v = acc[m][n][r] + bv;
        if (OUT_BF16)
          ((__bf16*)Cout)[(size_t)row * N + col] = (__bf16)v;
        else
          ((float*)Cout)[(size_t)row * N + col] = v;
      }
    }
  }
}

// ---------------- fused causal flash attention (v3) ----------------
// 8-wave blocks, shared K/V LDS: waves 0-3 own q-tile (31-p) [long], waves 4-7
// own q-tile p [short], one union KV loop of 32-p iters (short group predicated
// off after kvb > p). Doubles waves/CU vs v2 (16/CU, 4/SIMD). Per-CU load made
// constant by reversing pair order in the upper half of blockIdx.y.
// qkv: bf16 [B*T][3072]; q at col h*64, k at 1024+h*64, v at 2048+h*64.
__global__ __launch_bounds__(512) void attn_fused(const __bf16* __restrict__ qkv,
                                                  __bf16* __restrict__ attnb) {
  __shared__ __bf16 Kl[64][80];       // K tile [kv][d] (b128 stores, at LDS floor)
  __shared__ __bf16 Vt[64][80];       // V^T tile [d][kv], colblk ^= (row>>3)&7
  __shared__ __bf16 Pl[8][16][80];    // per-wave P [q][kv], colblk ^= (row>>2)&3
  const int tid = threadIdx.x, lane = tid & 63, w = tid >> 6;
  const int wl = w & 3;               // wave within group
  const int lgrp = lane >> 4, lcol = lane & 15;
  const int bh = blockIdx.y;
  const int pair = (bh & 16) ? (15 - blockIdx.x) : blockIdx.x;  // CU load balance
  const int b = bh >> 4, h = bh & 15;
  const __bf16* base = qkv + (size_t)b * 2048 * 3072;

  const int qt = (w < 4) ? (31 - pair) : pair;   // group 0 long, group 1 short
  const int qb = qt * 64;
  const int my_need = qt + 1;                    // KV tiles this group needs
  const int loop_len = 32 - pair;                // union loop length (= long's need)

  // staging geometry: 512 threads cover one 64x64 K chunk + one V chunk each
  const int kvr = tid >> 3;                      // 0..63
  const int d00 = (tid & 7) * 8;
  const int vcol = ((((kvr >> 3) ^ (tid & 7)) << 3) | (kvr & 7));  // Vt swizzle
  const __bf16* kvbase = base + 1024 + h * 64 + d00;

  // Q fragment (A-operand): row = lane&15, k(d) = (lane>>4)*8 + j (+32 per slice)
  const int qrow = qb + wl * 16 + lcol;
  const __bf16* qptr = base + (size_t)qrow * 3072 + h * 64;
  const bf16x8 qf0 = *(const bf16x8*)(qptr + lgrp * 8);
  const bf16x8 qf1 = *(const bf16x8*)(qptr + 32 + lgrp * 8);

  float m_r[4], l_r[4];
  f32x4 acc_o[4];
#pragma unroll
  for (int r = 0; r < 4; ++r) { m_r[r] = -1e30f; l_r[r] = 0.f; }
#pragma unroll
  for (int d = 0; d < 4; ++d) acc_o[d] = zero4();

  // prefetch tile 0 into registers (1 K-vec + 1 V-vec per thread)
  bf16x8 kf = *(const bf16x8*)(kvbase + (size_t)kvr * 3072);
  bf16x8 vf = *(const bf16x8*)(kvbase + (size_t)kvr * 3072 + 1024);

  for (int kvb = 0; kvb < loop_len; ++kvb) {
    const int kv0 = kvb * 64;
    __syncthreads();  // previous tile's LDS reads complete
    *(bf16x8*)&Kl[kvr][d00] = kf;
#pragma unroll
    for (int j = 0; j < 8; ++j) Vt[d00 + j][vcol] = vf[j];
    __syncthreads();
    // issue next tile's global loads (latency hides under compute below)
    if (kvb + 1 < loop_len) {
      const __bf16* p0 = kvbase + (size_t)(kv0 + 64 + kvr) * 3072;
      kf = *(const bf16x8*)p0;
      vf = *(const bf16x8*)(p0 + 1024);
    }

    if (kvb < my_need) {  // wave-uniform predicate (short group drops out)
      // S = Q @ K^T : B-operand col = kv = lane&15, k(d) contiguous
      f32x4 accs[4];
#pragma unroll
      for (int sub = 0; sub < 4; ++sub) {
        accs[sub] = zero4();
#pragma unroll
        for (int s = 0; s < 2; ++s) {
          const bf16x8 kb = *(const bf16x8*)&Kl[sub * 16 + lcol][s * 32 + lgrp * 8];
          accs[sub] = __builtin_amdgcn_mfma_f32_16x16x32_bf16(s ? qf1 : qf0, kb, accs[sub], 0, 0, 0);
        }
      }

      // scale + causal mask (D layout: col=lane&15 -> kv, row=4*(lane>>4)+r -> q)
      float sv[4][4];
      const int qg = qb + wl * 16 + lgrp * 4;
#pragma unroll
      for (int sub = 0; sub < 4; ++sub) {
        const int kvg = kv0 + sub * 16 + lcol;
#pragma unroll
        for (int r = 0; r < 4; ++r)
          sv[sub][r] = (kvg <= qg + r) ? accs[sub][r] * 0.125f : -1e30f;
      }

      // wave-parallel online softmax (16-lane-group reduction)
#pragma unroll
      for (int r = 0; r < 4; ++r) {
        float rm = fmaxf(fmaxf(sv[0][r], sv[1][r]), fmaxf(sv[2][r], sv[3][r]));
        rm = fmaxf(rm, __shfl_xor(rm, 1));
        rm = fmaxf(rm, __shfl_xor(rm, 2));
        rm = fmaxf(rm, __shfl_xor(rm, 4));
        rm = fmaxf(rm, __shfl_xor(rm, 8));
        const float nm = fmaxf(m_r[r], rm);
        const float sf = __expf(m_r[r] - nm);
        m_r[r] = nm;
        float rs = 0.f;
#pragma unroll
        for (int sub = 0; sub < 4; ++sub) {
          const float pv = __expf(sv[sub][r] - nm);
          sv[sub][r] = pv;
          rs += pv;
        }
        rs += __shfl_xor(rs, 1);
        rs += __shfl_xor(rs, 2);
        rs += __shfl_xor(rs, 4);
        rs += __shfl_xor(rs, 8);
        l_r[r] = l_r[r] * sf + rs;
#pragma unroll
        for (int d = 0; d < 4; ++d) acc_o[d][r] *= sf;
      }

      // P -> LDS (D-layout -> A-layout), swizzled: colblk ^= (row>>2)&3
#pragma unroll
      for (int sub = 0; sub < 4; ++sub) {
        const int pc = ((((sub * 2 + (lcol >> 3)) ^ lgrp) << 3) | (lcol & 7));
#pragma unroll
        for (int r = 0; r < 4; ++r)
          Pl[w][lgrp * 4 + r][pc] = (__bf16)sv[sub][r];
      }
      asm volatile("s_waitcnt lgkmcnt(0)" ::: "memory");
      __builtin_amdgcn_sched_barrier(0);  // rule 18: pin reads after the waitcnt

      // O += P @ V
#pragma unroll
      for (int s = 0; s < 2; ++s) {
        // A-frag read row = lcol -> key = (lcol>>2)&3, colblk = 4s+lgrp
        const bf16x8 pf = *(const bf16x8*)&Pl[w][lcol][((4 * s + lgrp) ^ ((lcol >> 2) & 3)) * 8];
#pragma unroll
        for (int d = 0; d < 4; ++d) {
          // B-frag read row = d*16+lcol -> key = (2d + (lcol>>3))&7, colblk = 4s+lgrp
          const bf16x8 vfr = *(const bf16x8*)&Vt[d * 16 + lcol][((4 * s + lgrp) ^ ((2 * d + (lcol >> 3)) & 7)) * 8];
          acc_o[d] = __builtin_amdgcn_mfma_f32_16x16x32_bf16(pf, vfr, acc_o[d], 0, 0, 0);
        }
      }
    }
  }

  // epilogue: O / l, write bf16 [B*T][1024] (= [B,T,H,D] flattened)
#pragma unroll
  for (int d = 0; d < 4; ++d) {
#pragma unroll
    for (int r = 0; r < 4; ++r) {
      const int q = qb + wl * 16 + lgrp * 4 + r;
      const int col = h * 64 + d * 16 + lcol;
      attnb[(size_t)(b * 2048 + q) * 1024 + col] = (__bf16)(acc_o[d][r] / l_r[r]);
    }
  }
}

extern "C" void kernel_launch(void* const* d_in, const int* in_sizes, int n_in,
                              void* d_out, int out_size, void* d_ws, size_t ws_size,
                              hipStream_t stream) {
  const float* x    = (const float*)d_in[0];
  const float* Wqkv = (const float*)d_in[1];
  const float* bqkv = (const float*)d_in[2];
  const float* Wout = (const float*)d_in[3];
  const float* bout = (const float*)d_in[4];
  float* out = (float*)d_out;

  // Workspace time-multiplexed, peak 32 MB:
  //   [0,24M)  qkvb  (bf16 [4096][3072])    -- dead after attn
  //   [24,30M) wqkvT (bf16 [3072][1024])    -- dead after GEMM1
  //   [24,32M) attnb (bf16 [4096][1024])    -- written by attn (over dead wqkvT)
  //   [0,2M)   woutT (bf16 [1024][1024])    -- transposed AFTER attn (over dead qkvb)
  char* ws = (char*)d_ws;
  __bf16* qkvb  = (__bf16*)(ws);
  __bf16* wqkvT = (__bf16*)(ws + (24u << 20));
  __bf16* attnb = (__bf16*)(ws + (24u << 20));
  __bf16* woutT = (__bf16*)(ws);

  transpose_cast<<<dim3(3072 / 32, 1024 / 32), dim3(32, 8), 0, stream>>>(Wqkv, wqkvT, 1024, 3072);

  gemm_bt<1, 1><<<dim3(3072 / 128, 4096 / 128), dim3(256), 0, stream>>>(
      (const void*)x, wqkvT, bqkv, (void*)qkvb, 4096, 3072, 1024);

  attn_fused<<<dim3(16, 2 * 16), dim3(512), 0, stream>>>(qkvb, attnb);

  transpose_cast<<<dim3(1024 / 32, 1024 / 32), dim3(32, 8), 0, stream>>>(Wout, woutT, 1024, 1024);

  gemm_bt<0, 0><<<dim3(1024 / 128, 4096 / 128), dim3(256), 0, stream>>>(
      (const void*)attnb, woutT, bout, (void*)out, 4096, 1024, 1024);
}

// Round 6
// 138.518 us; speedup vs baseline: 1.7767x; 1.1482x over previous
//
#include <hip/hip_runtime.h>
#include <hip/hip_bf16.h>
#include <stdint.h>

typedef __bf16 bf16x8 __attribute__((ext_vector_type(8)));
typedef float  f32x4  __attribute__((ext_vector_type(4)));

typedef __attribute__((address_space(1))) void gas1_t;
typedef __attribute__((address_space(3))) void as3_t;

__device__ __forceinline__ void gload_lds16(const void* g, void* l) {
  // width=16 global->LDS DMA; LDS dest is wave-uniform base + lane*16
  __builtin_amdgcn_global_load_lds((gas1_t*)g, (as3_t*)l, 16, 0, 0);
}

__device__ __forceinline__ f32x4 zero4() { f32x4 z = {0.f, 0.f, 0.f, 0.f}; return z; }

__device__ __forceinline__ unsigned pack_bf16x2(float a, float b) {
  __bf16 ha = (__bf16)a, hb = (__bf16)b;
  unsigned short ua = *(unsigned short*)&ha, ub = *(unsigned short*)&hb;
  return (unsigned)ua | ((unsigned)ub << 16);
}

// ---------------- transpose + cast: W[K][N] f32 -> WT[N][K] bf16 ----------------
__global__ void transpose_cast(const float* __restrict__ W, __bf16* __restrict__ WT,
                               int K, int N) {
  __shared__ float tile[32][33];
  const int n0 = blockIdx.x * 32, k0 = blockIdx.y * 32;
  const int tx = threadIdx.x, ty = threadIdx.y;
  for (int i = ty; i < 32; i += 8) tile[i][tx] = W[(size_t)(k0 + i) * N + n0 + tx];
  __syncthreads();
  for (int i = ty; i < 32; i += 8) WT[(size_t)(n0 + i) * K + k0 + tx] = (__bf16)tile[tx][i];
}

// ---------------- GEMM: C[M][N] = A[M][K] @ BT[N][K]^T + bias ----------------
// 128x128 tile, BK=32, 4 waves (2x2), each wave 64x64 = 4x4 subtiles of 16x16.
// A_F32: A is f32, reg-staged with on-the-fly bf16 convert. Else bf16 via global_load_lds.
template <int OUT_BF16, int A_F32>
__global__ __launch_bounds__(256) void gemm_bt(const void* __restrict__ Ap,
                                               const __bf16* __restrict__ BT,
                                               const float* __restrict__ bias,
                                               void* __restrict__ Cout,
                                               int M, int N, int K) {
  __shared__ __bf16 As[2][4096];  // [128][32] bf16, linear
  __shared__ __bf16 Bs[2][4096];
  const int tid = threadIdx.x;
  const int lane = tid & 63, w = tid >> 6;
  const int wr = w >> 1, wc = w & 1;
  const int lgrp = lane >> 4, lcol = lane & 15;
  const int m0 = blockIdx.y * 128, n0 = blockIdx.x * 128;

  f32x4 acc[4][4];
#pragma unroll
  for (int m = 0; m < 4; ++m)
#pragma unroll
    for (int n = 0; n < 4; ++n) acc[m][n] = zero4();

  const int nk = K >> 5;

  auto stageB = [&](int buf, int k0) {
#pragma unroll
    for (int q = 0; q < 2; ++q) {
      const int c = q * 256 + w * 64 + lane;  // 16B chunk id, 512 per tile
      const int row = c >> 2, kc = (c & 3) * 8;
      const int ldsoff = (q * 256 + w * 64) * 16;  // wave-uniform
      gload_lds16(BT + (size_t)(n0 + row) * K + k0 + kc, (char*)&Bs[buf][0] + ldsoff);
    }
  };
  auto stageA = [&](int buf, int k0) {
    if (A_F32) {
      const float* A = (const float*)Ap;
      const int c0 = tid * 2;               // two consecutive 8-elem chunks
      const int row = c0 >> 2, kc = (c0 & 3) * 8;
      const float* src = A + (size_t)(m0 + row) * K + k0 + kc;
      const f32x4 v0 = *(const f32x4*)(src);
      const f32x4 v1 = *(const f32x4*)(src + 4);
      const f32x4 v2 = *(const f32x4*)(src + 8);
      const f32x4 v3 = *(const f32x4*)(src + 12);
      bf16x8 o0, o1;
#pragma unroll
      for (int j = 0; j < 4; ++j) {
        o0[j] = (__bf16)v0[j]; o0[j + 4] = (__bf16)v1[j];
        o1[j] = (__bf16)v2[j]; o1[j + 4] = (__bf16)v3[j];
      }
      *(bf16x8*)((char*)&As[buf][0] + c0 * 16) = o0;
      *(bf16x8*)((char*)&As[buf][0] + c0 * 16 + 16) = o1;
    } else {
      const __bf16* A = (const __bf16*)Ap;
#pragma unroll
      for (int q = 0; q < 2; ++q) {
        const int c = q * 256 + w * 64 + lane;
        const int row = c >> 2, kc = (c & 3) * 8;
        const int ldsoff = (q * 256 + w * 64) * 16;
        gload_lds16(A + (size_t)(m0 + row) * K + k0 + kc, (char*)&As[buf][0] + ldsoff);
      }
    }
  };

  stageA(0, 0);
  stageB(0, 0);
  __syncthreads();
  int cur = 0;
  for (int t = 0; t < nk; ++t) {
    if (t + 1 < nk) { stageA(cur ^ 1, (t + 1) * 32); stageB(cur ^ 1, (t + 1) * 32); }
    bf16x8 af[4], bfr[4];
#pragma unroll
    for (int m = 0; m < 4; ++m)
      af[m] = *(const bf16x8*)&As[cur][(wr * 64 + m * 16 + lcol) * 32 + lgrp * 8];
#pragma unroll
    for (int n = 0; n < 4; ++n)
      bfr[n] = *(const bf16x8*)&Bs[cur][(wc * 64 + n * 16 + lcol) * 32 + lgrp * 8];
#pragma unroll
    for (int m = 0; m < 4; ++m)
#pragma unroll
      for (int n = 0; n < 4; ++n)
        acc[m][n] = __builtin_amdgcn_mfma_f32_16x16x32_bf16(af[m], bfr[n], acc[m][n], 0, 0, 0);
    __syncthreads();  // drains vmcnt (DMA staged) + lgkmcnt (reads/writes done)
    cur ^= 1;
  }

#pragma unroll
  for (int m = 0; m < 4; ++m) {
#pragma unroll
    for (int n = 0; n < 4; ++n) {
      const int col = n0 + wc * 64 + n * 16 + lcol;
      const float bv = bias[col];
#pragma unroll
      for (int r = 0; r < 4; ++r) {
        const int row = m0 + wr * 64 + m * 16 + lgrp * 4 + r;
        const float v = acc[m][n][r] + bv;
        if (OUT_BF16)
          ((__bf16*)Cout)[(size_t)row * N + col] = (__bf16)v;
        else
          ((float*)Cout)[(size_t)row * N + col] = v;
      }
    }
  }
}

// ---------------- fused causal flash attention (v4: swapped-operand MFMA) ----------------
// 8-wave blocks, shared K/V LDS (waves 0-3: q-tile 31-p, waves 4-7: q-tile p).
// QK^T computed as mfma(K,Q) -> S^T (col=q=lcol): each lane's 16 S-values belong to
// ONE q-row -> in-register softmax reduce + only 4 shfl_xor/iter (was 32).
// PV computed as mfma(V^T,P) -> O^T (col=q=lcol): rescale/divide use the lane's own
// m,l scalars (no broadcasts). Pl stores packed b64. Vt/Pl read indices unchanged.
// qkv: bf16 [B*T][3072]; q at col h*64, k at 1024+h*64, v at 2048+h*64.
__global__ __launch_bounds__(512) void attn_fused(const __bf16* __restrict__ qkv,
                                                  __bf16* __restrict__ attnb) {
  __shared__ __bf16 Kl[64][80];       // K tile [kv][d]
  __shared__ __bf16 Vt[64][80];       // V^T tile [d][kv], colblk ^= (row>>3)&7
  __shared__ __bf16 Pl[8][16][80];    // per-wave P [q][kv], colblk ^= (row>>2)&3
  const int tid = threadIdx.x, lane = tid & 63, w = tid >> 6;
  const int wl = w & 3;               // wave within group
  const int lgrp = lane >> 4, lcol = lane & 15;
  const int bh = blockIdx.y;
  const int pair = (bh & 16) ? (15 - blockIdx.x) : blockIdx.x;  // CU load balance
  const int b = bh >> 4, h = bh & 15;
  const __bf16* base = qkv + (size_t)b * 2048 * 3072;

  const int qt = (w < 4) ? (31 - pair) : pair;   // group 0 long, group 1 short
  const int qb = qt * 64;
  const int my_need = qt + 1;                    // KV tiles this group needs
  const int loop_len = 32 - pair;                // union loop length (= long's need)

  // staging geometry: 512 threads cover one 64x64 K chunk + one V chunk each
  const int kvr = tid >> 3;                      // 0..63
  const int d00 = (tid & 7) * 8;
  const int vcol = ((((kvr >> 3) ^ (tid & 7)) << 3) | (kvr & 7));  // Vt swizzle
  const __bf16* kvbase = base + 1024 + h * 64 + d00;

  // Q fragment (B-operand now): col = lane&15 = q, k(d) = lgrp*8 + j (+32 per slice)
  const int q_l = qb + wl * 16 + lcol;           // this lane's q-row
  const __bf16* qptr = base + (size_t)q_l * 3072 + h * 64;
  const bf16x8 qf0 = *(const bf16x8*)(qptr + lgrp * 8);
  const bf16x8 qf1 = *(const bf16x8*)(qptr + 32 + lgrp * 8);

  float m1 = -1e30f, l1 = 0.f;                   // own-row softmax state
  f32x4 acc_o[4];                                // O^T: acc_o[dsub], row d=4*lgrp+r
#pragma unroll
  for (int d = 0; d < 4; ++d) acc_o[d] = zero4();

  // prefetch tile 0 into registers (1 K-vec + 1 V-vec per thread)
  bf16x8 kf = *(const bf16x8*)(kvbase + (size_t)kvr * 3072);
  bf16x8 vf = *(const bf16x8*)(kvbase + (size_t)kvr * 3072 + 1024);

  for (int kvb = 0; kvb < loop_len; ++kvb) {
    const int kv0 = kvb * 64;
    __syncthreads();  // previous tile's LDS reads complete
    *(bf16x8*)&Kl[kvr][d00] = kf;
#pragma unroll
    for (int j = 0; j < 8; ++j) Vt[d00 + j][vcol] = vf[j];
    __syncthreads();
    // issue next tile's global loads (latency hides under compute below)
    if (kvb + 1 < loop_len) {
      const __bf16* p0 = kvbase + (size_t)(kv0 + 64 + kvr) * 3072;
      kf = *(const bf16x8*)p0;
      vf = *(const bf16x8*)(p0 + 1024);
    }

    if (kvb < my_need) {  // wave-uniform predicate (short group drops out)
      // S^T = K @ Q : D col = q = lcol, row = kv = sub*16 + 4*lgrp + r
      f32x4 accs[4];
#pragma unroll
      for (int sub = 0; sub < 4; ++sub) {
        accs[sub] = zero4();
#pragma unroll
        for (int s = 0; s < 2; ++s) {
          const bf16x8 kb = *(const bf16x8*)&Kl[sub * 16 + lcol][s * 32 + lgrp * 8];
          accs[sub] = __builtin_amdgcn_mfma_f32_16x16x32_bf16(kb, s ? qf1 : qf0, accs[sub], 0, 0, 0);
        }
      }

      // scale + causal mask: all 16 values belong to q-row q_l
      float sv[4][4];
#pragma unroll
      for (int sub = 0; sub < 4; ++sub) {
        const int kvg = kv0 + sub * 16 + lgrp * 4;
#pragma unroll
        for (int r = 0; r < 4; ++r)
          sv[sub][r] = (kvg + r <= q_l) ? accs[sub][r] * 0.125f : -1e30f;
      }

      // in-register row max (15-op tree) + 2 shfl across the 4 lanes sharing this row
      float mx[4];
#pragma unroll
      for (int sub = 0; sub < 4; ++sub)
        mx[sub] = fmaxf(fmaxf(sv[sub][0], sv[sub][1]), fmaxf(sv[sub][2], sv[sub][3]));
      float rm = fmaxf(fmaxf(mx[0], mx[1]), fmaxf(mx[2], mx[3]));
      rm = fmaxf(rm, __shfl_xor(rm, 16));
      rm = fmaxf(rm, __shfl_xor(rm, 32));
      const float nm = fmaxf(m1, rm);
      const float sf = __expf(m1 - nm);
      m1 = nm;

      // exp + in-register row sum (tree) + 2 shfl
      float ps[4];
#pragma unroll
      for (int sub = 0; sub < 4; ++sub) {
#pragma unroll
        for (int r = 0; r < 4; ++r) {
          const float pv = __expf(sv[sub][r] - nm);
          sv[sub][r] = pv;
        }
        ps[sub] = (sv[sub][0] + sv[sub][1]) + (sv[sub][2] + sv[sub][3]);
      }
      float rs = (ps[0] + ps[1]) + (ps[2] + ps[3]);
      rs += __shfl_xor(rs, 16);
      rs += __shfl_xor(rs, 32);
      l1 = l1 * sf + rs;

      // rescale O^T by own-row sf (no broadcast needed)
#pragma unroll
      for (int d = 0; d < 4; ++d)
#pragma unroll
        for (int r = 0; r < 4; ++r) acc_o[d][r] *= sf;

      // P -> LDS: packed b64 stores, row = q = lcol, cols sub*16+4*lgrp+{0..3}
      // swizzle colblk ^= (row>>2)&3 (read side identical to prior version)
#pragma unroll
      for (int sub = 0; sub < 4; ++sub) {
        uint2 pk;
        pk.x = pack_bf16x2(sv[sub][0], sv[sub][1]);
        pk.y = pack_bf16x2(sv[sub][2], sv[sub][3]);
        const int eoff = ((((sub * 2 + (lgrp >> 1)) ^ ((lcol >> 2) & 3)) << 3) | ((lgrp & 1) << 2));
        *(uint2*)&Pl[w][lcol][eoff] = pk;
      }
      asm volatile("s_waitcnt lgkmcnt(0)" ::: "memory");
      __builtin_amdgcn_sched_barrier(0);  // rule 18: pin reads after the waitcnt

      // O^T += V^T @ P : D col = q = lcol, row = d = dsub*16 + 4*lgrp + r
#pragma unroll
      for (int s = 0; s < 2; ++s) {
        const bf16x8 pf = *(const bf16x8*)&Pl[w][lcol][((4 * s + lgrp) ^ ((lcol >> 2) & 3)) * 8];
#pragma unroll
        for (int d = 0; d < 4; ++d) {
          const bf16x8 vfr = *(const bf16x8*)&Vt[d * 16 + lcol][((4 * s + lgrp) ^ ((2 * d + (lcol >> 3)) & 7)) * 8];
          acc_o[d] = __builtin_amdgcn_mfma_f32_16x16x32_bf16(vfr, pf, acc_o[d], 0, 0, 0);
        }
      }
    }
  }

  // epilogue: O^T -> bf16 [B*T][1024]; lane owns q-row q_l, d = dsub*16+4*lgrp+{0..3}
  const float inv_l = 1.0f / l1;
  __bf16* orow = attnb + (size_t)(b * 2048 + q_l) * 1024 + h * 64 + lgrp * 4;
#pragma unroll
  for (int d = 0; d < 4; ++d) {
    uint2 ov;
    ov.x = pack_bf16x2(acc_o[d][0] * inv_l, acc_o[d][1] * inv_l);
    ov.y = pack_bf16x2(acc_o[d][2] * inv_l, acc_o[d][3] * inv_l);
    *(uint2*)(orow + d * 16) = ov;
  }
}

extern "C" void kernel_launch(void* const* d_in, const int* in_sizes, int n_in,
                              void* d_out, int out_size, void* d_ws, size_t ws_size,
                              hipStream_t stream) {
  const float* x    = (const float*)d_in[0];
  const float* Wqkv = (const float*)d_in[1];
  const float* bqkv = (const float*)d_in[2];
  const float* Wout = (const float*)d_in[3];
  const float* bout = (const float*)d_in[4];
  float* out = (float*)d_out;

  // Workspace time-multiplexed, peak 32 MB:
  //   [0,24M)  qkvb  (bf16 [4096][3072])    -- dead after attn
  //   [24,30M) wqkvT (bf16 [3072][1024])    -- dead after GEMM1
  //   [24,32M) attnb (bf16 [4096][1024])    -- written by attn (over dead wqkvT)
  //   [0,2M)   woutT (bf16 [1024][1024])    -- transposed AFTER attn (over dead qkvb)
  char* ws = (char*)d_ws;
  __bf16* qkvb  = (__bf16*)(ws);
  __bf16* wqkvT = (__bf16*)(ws + (24u << 20));
  __bf16* attnb = (__bf16*)(ws + (24u << 20));
  __bf16* woutT = (__bf16*)(ws);

  transpose_cast<<<dim3(3072 / 32, 1024 / 32), dim3(32, 8), 0, stream>>>(Wqkv, wqkvT, 1024, 3072);

  gemm_bt<1, 1><<<dim3(3072 / 128, 4096 / 128), dim3(256), 0, stream>>>(
      (const void*)x, wqkvT, bqkv, (void*)qkvb, 4096, 3072, 1024);

  attn_fused<<<dim3(16, 2 * 16), dim3(512), 0, stream>>>(qkvb, attnb);

  transpose_cast<<<dim3(1024 / 32, 1024 / 32), dim3(32, 8), 0, stream>>>(Wout, woutT, 1024, 1024);

  gemm_bt<0, 0><<<dim3(1024 / 128, 4096 / 128), dim3(256), 0, stream>>>(
      (const void*)attnb, woutT, bout, (void*)out, 4096, 1024, 1024);
}

// Round 7
// 129.777 us; speedup vs baseline: 1.8963x; 1.0674x over previous
//
#include <hip/hip_runtime.h>
#include <hip/hip_bf16.h>
#include <stdint.h>

typedef __bf16 bf16x8 __attribute__((ext_vector_type(8)));
typedef float  f32x4  __attribute__((ext_vector_type(4)));

typedef __attribute__((address_space(1))) void gas1_t;
typedef __attribute__((address_space(3))) void as3_t;

__device__ __forceinline__ void gload_lds16(const void* g, void* l) {
  // width=16 global->LDS DMA; LDS dest is wave-uniform base + lane*16
  __builtin_amdgcn_global_load_lds((gas1_t*)g, (as3_t*)l, 16, 0, 0);
}

__device__ __forceinline__ f32x4 zero4() { f32x4 z = {0.f, 0.f, 0.f, 0.f}; return z; }

__device__ __forceinline__ unsigned pack_bf16x2(float a, float b) {
  __bf16 ha = (__bf16)a, hb = (__bf16)b;
  unsigned short ua = *(unsigned short*)&ha, ub = *(unsigned short*)&hb;
  return (unsigned)ua | ((unsigned)ub << 16);
}

// ---------------- float -> bf16 cast, 8 elems/thread ----------------
__global__ void cvt_f32_to_bf16(const float* __restrict__ in, __bf16* __restrict__ out, int n) {
  int i = (blockIdx.x * 256 + threadIdx.x) * 8;
  if (i >= n) return;
  const f32x4 v0 = *(const f32x4*)(in + i);
  const f32x4 v1 = *(const f32x4*)(in + i + 4);
  bf16x8 o;
#pragma unroll
  for (int j = 0; j < 4; ++j) { o[j] = (__bf16)v0[j]; o[j + 4] = (__bf16)v1[j]; }
  *(bf16x8*)(out + i) = o;
}

// ---------------- transpose + cast: W[K][N] f32 -> WT[N][K] bf16 ----------------
__global__ void transpose_cast(const float* __restrict__ W, __bf16* __restrict__ WT,
                               int K, int N) {
  __shared__ float tile[32][33];
  const int n0 = blockIdx.x * 32, k0 = blockIdx.y * 32;
  const int tx = threadIdx.x, ty = threadIdx.y;
  for (int i = ty; i < 32; i += 8) tile[i][tx] = W[(size_t)(k0 + i) * N + n0 + tx];
  __syncthreads();
  for (int i = ty; i < 32; i += 8) WT[(size_t)(n0 + i) * K + k0 + tx] = (__bf16)tile[tx][i];
}

// ---------------- GEMM: C[M][N] = A[M][K] @ BT[N][K]^T + bias ----------------
// 128x128 tile, BK=32, 4 waves (2x2), each wave 64x64 = 4x4 subtiles of 16x16.
// A_F32: A is f32, reg-staged with on-the-fly bf16 convert. Else bf16 via global_load_lds.
template <int OUT_BF16, int A_F32>
__global__ __launch_bounds__(256) void gemm_bt(const void* __restrict__ Ap,
                                               const __bf16* __restrict__ BT,
                                               const float* __restrict__ bias,
                                               void* __restrict__ Cout,
                                               int M, int N, int K) {
  __shared__ __bf16 As[2][4096];  // [128][32] bf16, linear
  __shared__ __bf16 Bs[2][4096];
  const int tid = threadIdx.x;
  const int lane = tid & 63, w = tid >> 6;
  const int wr = w >> 1, wc = w & 1;
  const int lgrp = lane >> 4, lcol = lane & 15;
  const int m0 = blockIdx.y * 128, n0 = blockIdx.x * 128;

  f32x4 acc[4][4];
#pragma unroll
  for (int m = 0; m < 4; ++m)
#pragma unroll
    for (int n = 0; n < 4; ++n) acc[m][n] = zero4();

  const int nk = K >> 5;

  auto stageB = [&](int buf, int k0) {
#pragma unroll
    for (int q = 0; q < 2; ++q) {
      const int c = q * 256 + w * 64 + lane;  // 16B chunk id, 512 per tile
      const int row = c >> 2, kc = (c & 3) * 8;
      const int ldsoff = (q * 256 + w * 64) * 16;  // wave-uniform
      gload_lds16(BT + (size_t)(n0 + row) * K + k0 + kc, (char*)&Bs[buf][0] + ldsoff);
    }
  };
  auto stageA = [&](int buf, int k0) {
    if (A_F32) {
      const float* A = (const float*)Ap;
      const int c0 = tid * 2;               // two consecutive 8-elem chunks
      const int row = c0 >> 2, kc = (c0 & 3) * 8;
      const float* src = A + (size_t)(m0 + row) * K + k0 + kc;
      const f32x4 v0 = *(const f32x4*)(src);
      const f32x4 v1 = *(const f32x4*)(src + 4);
      const f32x4 v2 = *(const f32x4*)(src + 8);
      const f32x4 v3 = *(const f32x4*)(src + 12);
      bf16x8 o0, o1;
#pragma unroll
      for (int j = 0; j < 4; ++j) {
        o0[j] = (__bf16)v0[j]; o0[j + 4] = (__bf16)v1[j];
        o1[j] = (__bf16)v2[j]; o1[j + 4] = (__bf16)v3[j];
      }
      *(bf16x8*)((char*)&As[buf][0] + c0 * 16) = o0;
      *(bf16x8*)((char*)&As[buf][0] + c0 * 16 + 16) = o1;
    } else {
      const __bf16* A = (const __bf16*)Ap;
#pragma unroll
      for (int q = 0; q < 2; ++q) {
        const int c = q * 256 + w * 64 + lane;
        const int row = c >> 2, kc = (c & 3) * 8;
        const int ldsoff = (q * 256 + w * 64) * 16;
        gload_lds16(A + (size_t)(m0 + row) * K + k0 + kc, (char*)&As[buf][0] + ldsoff);
      }
    }
  };

  stageA(0, 0);
  stageB(0, 0);
  __syncthreads();
  int cur = 0;
  for (int t = 0; t < nk; ++t) {
    if (t + 1 < nk) { stageA(cur ^ 1, (t + 1) * 32); stageB(cur ^ 1, (t + 1) * 32); }
    bf16x8 af[4], bfr[4];
#pragma unroll
    for (int m = 0; m < 4; ++m)
      af[m] = *(const bf16x8*)&As[cur][(wr * 64 + m * 16 + lcol) * 32 + lgrp * 8];
#pragma unroll
    for (int n = 0; n < 4; ++n)
      bfr[n] = *(const bf16x8*)&Bs[cur][(wc * 64 + n * 16 + lcol) * 32 + lgrp * 8];
    __builtin_amdgcn_s_setprio(1);
#pragma unroll
    for (int m = 0; m < 4; ++m)
#pragma unroll
      for (int n = 0; n < 4; ++n)
        acc[m][n] = __builtin_amdgcn_mfma_f32_16x16x32_bf16(af[m], bfr[n], acc[m][n], 0, 0, 0);
    __builtin_amdgcn_s_setprio(0);
    __syncthreads();  // drains vmcnt (DMA staged) + lgkmcnt (reads/writes done)
    cur ^= 1;
  }

#pragma unroll
  for (int m = 0; m < 4; ++m) {
#pragma unroll
    for (int n = 0; n < 4; ++n) {
      const int col = n0 + wc * 64 + n * 16 + lcol;
      const float bv = bias[col];
#pragma unroll
      for (int r = 0; r < 4; ++r) {
        const int row = m0 + wr * 64 + m * 16 + lgrp * 4 + r;
        const float v = acc[m][n][r] + bv;
        if (OUT_BF16)
          ((__bf16*)Cout)[(size_t)row * N + col] = (__bf16)v;
        else
          ((float*)Cout)[(size_t)row * N + col] = v;
      }
    }
  }
}

// ---------------- fused causal flash attention (v4: swapped-operand MFMA) ----------------
// 8-wave blocks, shared K/V LDS (waves 0-3: q-tile 31-p, waves 4-7: q-tile p).
// QK^T computed as mfma(K,Q) -> S^T (col=q=lcol): each lane's 16 S-values belong to
// ONE q-row -> in-register softmax reduce + only 4 shfl_xor/iter. PV as mfma(V^T,P)
// -> O^T: rescale/divide use the lane's own m,l scalars. T5 setprio around MFMAs.
// qkv: bf16 [B*T][3072]; q at col h*64, k at 1024+h*64, v at 2048+h*64.
__global__ __launch_bounds__(512) void attn_fused(const __bf16* __restrict__ qkv,
                                                  __bf16* __restrict__ attnb) {
  __shared__ __bf16 Kl[64][80];       // K tile [kv][d]
  __shared__ __bf16 Vt[64][80];       // V^T tile [d][kv], colblk ^= (row>>3)&7
  __shared__ __bf16 Pl[8][16][80];    // per-wave P [q][kv], colblk ^= (row>>2)&3
  const int tid = threadIdx.x, lane = tid & 63, w = tid >> 6;
  const int wl = w & 3;               // wave within group
  const int lgrp = lane >> 4, lcol = lane & 15;
  const int bh = blockIdx.y;
  const int pair = (bh & 16) ? (15 - blockIdx.x) : blockIdx.x;  // CU load balance
  const int b = bh >> 4, h = bh & 15;
  const __bf16* base = qkv + (size_t)b * 2048 * 3072;

  const int qt = (w < 4) ? (31 - pair) : pair;   // group 0 long, group 1 short
  const int qb = qt * 64;
  const int my_need = qt + 1;                    // KV tiles this group needs
  const int loop_len = 32 - pair;                // union loop length (= long's need)

  // staging geometry: 512 threads cover one 64x64 K chunk + one V chunk each
  const int kvr = tid >> 3;                      // 0..63
  const int d00 = (tid & 7) * 8;
  const int vcol = ((((kvr >> 3) ^ (tid & 7)) << 3) | (kvr & 7));  // Vt swizzle
  const __bf16* kvbase = base + 1024 + h * 64 + d00;

  // Q fragment (B-operand now): col = lane&15 = q, k(d) = lgrp*8 + j (+32 per slice)
  const int q_l = qb + wl * 16 + lcol;           // this lane's q-row
  const __bf16* qptr = base + (size_t)q_l * 3072 + h * 64;
  const bf16x8 qf0 = *(const bf16x8*)(qptr + lgrp * 8);
  const bf16x8 qf1 = *(const bf16x8*)(qptr + 32 + lgrp * 8);

  float m1 = -1e30f, l1 = 0.f;                   // own-row softmax state
  f32x4 acc_o[4];                                // O^T: acc_o[dsub], row d=4*lgrp+r
#pragma unroll
  for (int d = 0; d < 4; ++d) acc_o[d] = zero4();

  // prefetch tile 0 into registers (1 K-vec + 1 V-vec per thread)
  bf16x8 kf = *(const bf16x8*)(kvbase + (size_t)kvr * 3072);
  bf16x8 vf = *(const bf16x8*)(kvbase + (size_t)kvr * 3072 + 1024);

  for (int kvb = 0; kvb < loop_len; ++kvb) {
    const int kv0 = kvb * 64;
    __syncthreads();  // previous tile's LDS reads complete
    *(bf16x8*)&Kl[kvr][d00] = kf;
#pragma unroll
    for (int j = 0; j < 8; ++j) Vt[d00 + j][vcol] = vf[j];
    __syncthreads();
    // issue next tile's global loads (latency hides under compute below)
    if (kvb + 1 < loop_len) {
      const __bf16* p0 = kvbase + (size_t)(kv0 + 64 + kvr) * 3072;
      kf = *(const bf16x8*)p0;
      vf = *(const bf16x8*)(p0 + 1024);
    }

    if (kvb < my_need) {  // wave-uniform predicate (short group drops out)
      // S^T = K @ Q : D col = q = lcol, row = kv = sub*16 + 4*lgrp + r
      f32x4 accs[4];
      __builtin_amdgcn_s_setprio(1);
#pragma unroll
      for (int sub = 0; sub < 4; ++sub) {
        accs[sub] = zero4();
#pragma unroll
        for (int s = 0; s < 2; ++s) {
          const bf16x8 kb = *(const bf16x8*)&Kl[sub * 16 + lcol][s * 32 + lgrp * 8];
          accs[sub] = __builtin_amdgcn_mfma_f32_16x16x32_bf16(kb, s ? qf1 : qf0, accs[sub], 0, 0, 0);
        }
      }
      __builtin_amdgcn_s_setprio(0);

      // scale + causal mask: all 16 values belong to q-row q_l
      float sv[4][4];
#pragma unroll
      for (int sub = 0; sub < 4; ++sub) {
        const int kvg = kv0 + sub * 16 + lgrp * 4;
#pragma unroll
        for (int r = 0; r < 4; ++r)
          sv[sub][r] = (kvg + r <= q_l) ? accs[sub][r] * 0.125f : -1e30f;
      }

      // in-register row max (tree) + 2 shfl across the 4 lanes sharing this row
      float mx[4];
#pragma unroll
      for (int sub = 0; sub < 4; ++sub)
        mx[sub] = fmaxf(fmaxf(sv[sub][0], sv[sub][1]), fmaxf(sv[sub][2], sv[sub][3]));
      float rm = fmaxf(fmaxf(mx[0], mx[1]), fmaxf(mx[2], mx[3]));
      rm = fmaxf(rm, __shfl_xor(rm, 16));
      rm = fmaxf(rm, __shfl_xor(rm, 32));
      const float nm = fmaxf(m1, rm);
      const float sf = __expf(m1 - nm);
      m1 = nm;

      // exp + in-register row sum (tree) + 2 shfl
      float ps[4];
#pragma unroll
      for (int sub = 0; sub < 4; ++sub) {
#pragma unroll
        for (int r = 0; r < 4; ++r) {
          const float pv = __expf(sv[sub][r] - nm);
          sv[sub][r] = pv;
        }
        ps[sub] = (sv[sub][0] + sv[sub][1]) + (sv[sub][2] + sv[sub][3]);
      }
      float rs = (ps[0] + ps[1]) + (ps[2] + ps[3]);
      rs += __shfl_xor(rs, 16);
      rs += __shfl_xor(rs, 32);
      l1 = l1 * sf + rs;

      // rescale O^T by own-row sf (no broadcast needed)
#pragma unroll
      for (int d = 0; d < 4; ++d)
#pragma unroll
        for (int r = 0; r < 4; ++r) acc_o[d][r] *= sf;

      // P -> LDS: packed b64 stores, row = q = lcol, cols sub*16+4*lgrp+{0..3}
      // swizzle colblk ^= (row>>2)&3 (read side identical to prior version)
#pragma unroll
      for (int sub = 0; sub < 4; ++sub) {
        uint2 pk;
        pk.x = pack_bf16x2(sv[sub][0], sv[sub][1]);
        pk.y = pack_bf16x2(sv[sub][2], sv[sub][3]);
        const int eoff = ((((sub * 2 + (lgrp >> 1)) ^ ((lcol >> 2) & 3)) << 3) | ((lgrp & 1) << 2));
        *(uint2*)&Pl[w][lcol][eoff] = pk;
      }
      asm volatile("s_waitcnt lgkmcnt(0)" ::: "memory");
      __builtin_amdgcn_sched_barrier(0);  // rule 18: pin reads after the waitcnt

      // O^T += V^T @ P : D col = q = lcol, row = d = dsub*16 + 4*lgrp + r
      __builtin_amdgcn_s_setprio(1);
#pragma unroll
      for (int s = 0; s < 2; ++s) {
        const bf16x8 pf = *(const bf16x8*)&Pl[w][lcol][((4 * s + lgrp) ^ ((lcol >> 2) & 3)) * 8];
#pragma unroll
        for (int d = 0; d < 4; ++d) {
          const bf16x8 vfr = *(const bf16x8*)&Vt[d * 16 + lcol][((4 * s + lgrp) ^ ((2 * d + (lcol >> 3)) & 7)) * 8];
          acc_o[d] = __builtin_amdgcn_mfma_f32_16x16x32_bf16(vfr, pf, acc_o[d], 0, 0, 0);
        }
      }
      __builtin_amdgcn_s_setprio(0);
    }
  }

  // epilogue: O^T -> bf16 [B*T][1024]; lane owns q-row q_l, d = dsub*16+4*lgrp+{0..3}
  const float inv_l = 1.0f / l1;
  __bf16* orow = attnb + (size_t)(b * 2048 + q_l) * 1024 + h * 64 + lgrp * 4;
#pragma unroll
  for (int d = 0; d < 4; ++d) {
    uint2 ov;
    ov.x = pack_bf16x2(acc_o[d][0] * inv_l, acc_o[d][1] * inv_l);
    ov.y = pack_bf16x2(acc_o[d][2] * inv_l, acc_o[d][3] * inv_l);
    *(uint2*)(orow + d * 16) = ov;
  }
}

extern "C" void kernel_launch(void* const* d_in, const int* in_sizes, int n_in,
                              void* d_out, int out_size, void* d_ws, size_t ws_size,
                              hipStream_t stream) {
  const float* x    = (const float*)d_in[0];
  const float* Wqkv = (const float*)d_in[1];
  const float* bqkv = (const float*)d_in[2];
  const float* Wout = (const float*)d_in[3];
  const float* bout = (const float*)d_in[4];
  float* out = (float*)d_out;

  // Workspace plan (time-multiplexed):
  //   [0,24M)   qkvb  (bf16 [4096][3072])  -- dead after attn
  //   [24,30M)  wqkvT (bf16 [3072][1024])  -- dead after GEMM1
  //   [30,38M)  xb    (bf16 [4096][1024])  -- only if ws_size >= 38M
  //   [24,32M)  attnb (bf16 [4096][1024])  -- written by attn (over dead wqkvT)
  //   [0,2M)    woutT (bf16 [1024][1024])  -- transposed AFTER attn (over dead qkvb)
  char* ws = (char*)d_ws;
  __bf16* qkvb  = (__bf16*)(ws);
  __bf16* wqkvT = (__bf16*)(ws + (24u << 20));
  __bf16* xb    = (__bf16*)(ws + (30u << 20));
  __bf16* attnb = (__bf16*)(ws + (24u << 20));
  __bf16* woutT = (__bf16*)(ws);

  const bool big_ws = ws_size >= ((size_t)38 << 20);  // constant per process

  transpose_cast<<<dim3(3072 / 32, 1024 / 32), dim3(32, 8), 0, stream>>>(Wqkv, wqkvT, 1024, 3072);

  if (big_ws) {
    cvt_f32_to_bf16<<<dim3(4096 * 1024 / 2048), dim3(256), 0, stream>>>(x, xb, 4096 * 1024);
    gemm_bt<1, 0><<<dim3(3072 / 128, 4096 / 128), dim3(256), 0, stream>>>(
        (const void*)xb, wqkvT, bqkv, (void*)qkvb, 4096, 3072, 1024);
  } else {
    gemm_bt<1, 1><<<dim3(3072 / 128, 4096 / 128), dim3(256), 0, stream>>>(
        (const void*)x, wqkvT, bqkv, (void*)qkvb, 4096, 3072, 1024);
  }

  attn_fused<<<dim3(16, 2 * 16), dim3(512), 0, stream>>>(qkvb, attnb);

  transpose_cast<<<dim3(1024 / 32, 1024 / 32), dim3(32, 8), 0, stream>>>(Wout, woutT, 1024, 1024);

  gemm_bt<0, 0><<<dim3(1024 / 128, 4096 / 128), dim3(256), 0, stream>>>(
      (const void*)attnb, woutT, bout, (void*)out, 4096, 1024, 1024);
}

// Round 8
// 123.644 us; speedup vs baseline: 1.9904x; 1.0496x over previous
//
#include <hip/hip_runtime.h>
#include <hip/hip_bf16.h>
#include <stdint.h>

typedef __bf16 bf16x8 __attribute__((ext_vector_type(8)));
typedef float  f32x4  __attribute__((ext_vector_type(4)));

typedef __attribute__((address_space(1))) void gas1_t;
typedef __attribute__((address_space(3))) void as3_t;

__device__ __forceinline__ void gload_lds16(const void* g, void* l) {
  // width=16 global->LDS DMA; LDS dest is wave-uniform base + lane*16
  __builtin_amdgcn_global_load_lds((gas1_t*)g, (as3_t*)l, 16, 0, 0);
}

__device__ __forceinline__ f32x4 zero4() { f32x4 z = {0.f, 0.f, 0.f, 0.f}; return z; }

__device__ __forceinline__ unsigned pack_bf16x2(float a, float b) {
  __bf16 ha = (__bf16)a, hb = (__bf16)b;
  unsigned short ua = *(unsigned short*)&ha, ub = *(unsigned short*)&hb;
  return (unsigned)ua | ((unsigned)ub << 16);
}

// ---------------- float -> bf16 cast, 8 elems/thread ----------------
__global__ void cvt_f32_to_bf16(const float* __restrict__ in, __bf16* __restrict__ out, int n) {
  int i = (blockIdx.x * 256 + threadIdx.x) * 8;
  if (i >= n) return;
  const f32x4 v0 = *(const f32x4*)(in + i);
  const f32x4 v1 = *(const f32x4*)(in + i + 4);
  bf16x8 o;
#pragma unroll
  for (int j = 0; j < 4; ++j) { o[j] = (__bf16)v0[j]; o[j + 4] = (__bf16)v1[j]; }
  *(bf16x8*)(out + i) = o;
}

// ---------------- transpose + cast: W[K][N] f32 -> WT[N][K] bf16 ----------------
__global__ void transpose_cast(const float* __restrict__ W, __bf16* __restrict__ WT,
                               int K, int N) {
  __shared__ float tile[32][33];
  const int n0 = blockIdx.x * 32, k0 = blockIdx.y * 32;
  const int tx = threadIdx.x, ty = threadIdx.y;
  for (int i = ty; i < 32; i += 8) tile[i][tx] = W[(size_t)(k0 + i) * N + n0 + tx];
  __syncthreads();
  for (int i = ty; i < 32; i += 8) WT[(size_t)(n0 + i) * K + k0 + tx] = (__bf16)tile[tx][i];
}

// ---------------- GEMM: C[M][N] = A[M][K] @ BT[N][K]^T + bias ----------------
// 128x128 tile, BK=32, 4 waves (2x2), each wave 64x64 = 4x4 subtiles of 16x16.
// A_F32: A is f32, reg-staged with on-the-fly bf16 convert. Else bf16 via global_load_lds.
// SCALE_Q: multiply columns < 1024 by 0.125 (folds attention 1/sqrt(D) into Q).
template <int OUT_BF16, int A_F32, int SCALE_Q>
__global__ __launch_bounds__(256) void gemm_bt(const void* __restrict__ Ap,
                                               const __bf16* __restrict__ BT,
                                               const float* __restrict__ bias,
                                               void* __restrict__ Cout,
                                               int M, int N, int K) {
  __shared__ __bf16 As[2][4096];  // [128][32] bf16, linear
  __shared__ __bf16 Bs[2][4096];
  const int tid = threadIdx.x;
  const int lane = tid & 63, w = tid >> 6;
  const int wr = w >> 1, wc = w & 1;
  const int lgrp = lane >> 4, lcol = lane & 15;
  const int m0 = blockIdx.y * 128, n0 = blockIdx.x * 128;

  f32x4 acc[4][4];
#pragma unroll
  for (int m = 0; m < 4; ++m)
#pragma unroll
    for (int n = 0; n < 4; ++n) acc[m][n] = zero4();

  const int nk = K >> 5;

  auto stageB = [&](int buf, int k0) {
#pragma unroll
    for (int q = 0; q < 2; ++q) {
      const int c = q * 256 + w * 64 + lane;  // 16B chunk id, 512 per tile
      const int row = c >> 2, kc = (c & 3) * 8;
      const int ldsoff = (q * 256 + w * 64) * 16;  // wave-uniform
      gload_lds16(BT + (size_t)(n0 + row) * K + k0 + kc, (char*)&Bs[buf][0] + ldsoff);
    }
  };
  auto stageA = [&](int buf, int k0) {
    if (A_F32) {
      const float* A = (const float*)Ap;
      const int c0 = tid * 2;               // two consecutive 8-elem chunks
      const int row = c0 >> 2, kc = (c0 & 3) * 8;
      const float* src = A + (size_t)(m0 + row) * K + k0 + kc;
      const f32x4 v0 = *(const f32x4*)(src);
      const f32x4 v1 = *(const f32x4*)(src + 4);
      const f32x4 v2 = *(const f32x4*)(src + 8);
      const f32x4 v3 = *(const f32x4*)(src + 12);
      bf16x8 o0, o1;
#pragma unroll
      for (int j = 0; j < 4; ++j) {
        o0[j] = (__bf16)v0[j]; o0[j + 4] = (__bf16)v1[j];
        o1[j] = (__bf16)v2[j]; o1[j + 4] = (__bf16)v3[j];
      }
      *(bf16x8*)((char*)&As[buf][0] + c0 * 16) = o0;
      *(bf16x8*)((char*)&As[buf][0] + c0 * 16 + 16) = o1;
    } else {
      const __bf16* A = (const __bf16*)Ap;
#pragma unroll
      for (int q = 0; q < 2; ++q) {
        const int c = q * 256 + w * 64 + lane;
        const int row = c >> 2, kc = (c & 3) * 8;
        const int ldsoff = (q * 256 + w * 64) * 16;
        gload_lds16(A + (size_t)(m0 + row) * K + k0 + kc, (char*)&As[buf][0] + ldsoff);
      }
    }
  };

  stageA(0, 0);
  stageB(0, 0);
  __syncthreads();
  int cur = 0;
  for (int t = 0; t < nk; ++t) {
    if (t + 1 < nk) { stageA(cur ^ 1, (t + 1) * 32); stageB(cur ^ 1, (t + 1) * 32); }
    bf16x8 af[4], bfr[4];
#pragma unroll
    for (int m = 0; m < 4; ++m)
      af[m] = *(const bf16x8*)&As[cur][(wr * 64 + m * 16 + lcol) * 32 + lgrp * 8];
#pragma unroll
    for (int n = 0; n < 4; ++n)
      bfr[n] = *(const bf16x8*)&Bs[cur][(wc * 64 + n * 16 + lcol) * 32 + lgrp * 8];
    __builtin_amdgcn_s_setprio(1);
#pragma unroll
    for (int m = 0; m < 4; ++m)
#pragma unroll
      for (int n = 0; n < 4; ++n)
        acc[m][n] = __builtin_amdgcn_mfma_f32_16x16x32_bf16(af[m], bfr[n], acc[m][n], 0, 0, 0);
    __builtin_amdgcn_s_setprio(0);
    __syncthreads();  // drains vmcnt (DMA staged) + lgkmcnt (reads/writes done)
    cur ^= 1;
  }

#pragma unroll
  for (int m = 0; m < 4; ++m) {
#pragma unroll
    for (int n = 0; n < 4; ++n) {
      const int col = n0 + wc * 64 + n * 16 + lcol;
      const float bv = bias[col];
#pragma unroll
      for (int r = 0; r < 4; ++r) {
        const int row = m0 + wr * 64 + m * 16 + lgrp * 4 + r;
        float v = acc[m][n][r] + bv;
        if (SCALE_Q && col < 1024) v *= 0.125f;
        if (OUT_BF16)
          ((__bf16*)Cout)[(size_t)row * N + col] = (__bf16)v;
        else
          ((float*)Cout)[(size_t)row * N + col] = v;
      }
    }
  }
}

// ---------------- fused causal flash attention (v5: 128q x 128kv rounds) ----------------
// Grid (16, B*H); block owns 128 q-rows (8 waves x 16), KV tile = 128 (two 64-halves).
// All waves compute every round; round count per block = xp+1; CU pair (x,15-x) -> 17.
// Swapped-operand MFMA (S^T / O^T, col=q=lcol) -> in-register softmax, 4 shfl/round.
// Q pre-scaled by 0.125 in GEMM1. Masking only on the diagonal round (kvb==xp).
// qkv: bf16 [B*T][3072]; q at col h*64, k at 1024+h*64, v at 2048+h*64.
__global__ __launch_bounds__(512, 4) void attn_fused(const __bf16* __restrict__ qkv,
                                                     __bf16* __restrict__ attnb) {
  __shared__ __bf16 Kl[2][64][80];    // K halves [kv][d]
  __shared__ __bf16 Vt[2][64][80];    // V^T halves [d][kv], colblk ^= (kv>>3)&7
  __shared__ __bf16 Pl[8][16][80];    // per-wave P^T [q][kv], colblk ^= (q>>2)&3
  const int tid = threadIdx.x, lane = tid & 63, w = tid >> 6;
  const int lgrp = lane >> 4, lcol = lane & 15;
  const int bh = blockIdx.y;
  const int xp = (bh & 16) ? (15 - blockIdx.x) : blockIdx.x;  // CU pair balance
  const int b = bh >> 4, h = bh & 15;
  const __bf16* base = qkv + (size_t)b * 2048 * 3072;

  const int qb = xp * 128;            // block q start
  const int rw = qb + w * 16;         // wave q start
  const int nkv = xp + 1;             // number of 128-kv rounds

  // staging: thread covers K/V rows krow and krow+64, cols d00..d00+7
  const int krow = tid >> 3;          // 0..63
  const int d00 = (tid & 7) * 8;
  const int vcol = ((((krow >> 3) ^ (tid & 7)) << 3) | (krow & 7));  // Vt swizzle
  const __bf16* kvp = base + 1024 + h * 64 + d00;

  // Q fragment (B-operand): col = q = lcol, k(d) = lgrp*8 + j (+32 per slice)
  const int q_l = rw + lcol;          // this lane's q-row
  const __bf16* qptr = base + (size_t)q_l * 3072 + h * 64;
  const bf16x8 qf0 = *(const bf16x8*)(qptr + lgrp * 8);
  const bf16x8 qf1 = *(const bf16x8*)(qptr + 32 + lgrp * 8);

  float m1 = -1e30f, l1 = 0.f;        // own-row softmax state
  f32x4 acc_o[4];                     // O^T: row d = dsub*16 + 4*lgrp + r
#pragma unroll
  for (int d = 0; d < 4; ++d) acc_o[d] = zero4();

  // prefetch round 0 (2 K-vecs + 2 V-vecs per thread)
  bf16x8 kf0 = *(const bf16x8*)(kvp + (size_t)krow * 3072);
  bf16x8 vf0 = *(const bf16x8*)(kvp + (size_t)krow * 3072 + 1024);
  bf16x8 kf1 = *(const bf16x8*)(kvp + (size_t)(krow + 64) * 3072);
  bf16x8 vf1 = *(const bf16x8*)(kvp + (size_t)(krow + 64) * 3072 + 1024);

  for (int kvb = 0; kvb < nkv; ++kvb) {
    const int kv0 = kvb * 128;
    __syncthreads();  // previous round's LDS reads complete
    *(bf16x8*)&Kl[0][krow][d00] = kf0;
    *(bf16x8*)&Kl[1][krow][d00] = kf1;
#pragma unroll
    for (int j = 0; j < 8; ++j) {
      Vt[0][d00 + j][vcol] = vf0[j];
      Vt[1][d00 + j][vcol] = vf1[j];
    }
    __syncthreads();
    // issue next round's global loads (hide HBM latency under compute)
    if (kvb + 1 < nkv) {
      const __bf16* p = kvp + (size_t)(kv0 + 128 + krow) * 3072;
      kf0 = *(const bf16x8*)p;
      vf0 = *(const bf16x8*)(p + 1024);
      kf1 = *(const bf16x8*)(p + (size_t)64 * 3072);
      vf1 = *(const bf16x8*)(p + (size_t)64 * 3072 + 1024);
    }

    const bool diag = (kvb == xp);          // only final round needs masking
    const bool skip1 = diag && (w < 4);     // waves 0-3: upper kv-half fully masked

    // S^T = K @ Q : D col = q = lcol, row = kv = sub*16 + 4*lgrp + r
    f32x4 accs[8];
    __builtin_amdgcn_s_setprio(1);
#pragma unroll
    for (int sub = 0; sub < 4; ++sub) {
      accs[sub] = zero4();
#pragma unroll
      for (int s = 0; s < 2; ++s) {
        const bf16x8 kb = *(const bf16x8*)&Kl[0][sub * 16 + lcol][s * 32 + lgrp * 8];
        accs[sub] = __builtin_amdgcn_mfma_f32_16x16x32_bf16(kb, s ? qf1 : qf0, accs[sub], 0, 0, 0);
      }
    }
    if (!skip1) {
#pragma unroll
      for (int sub = 0; sub < 4; ++sub) {
        accs[4 + sub] = zero4();
#pragma unroll
        for (int s = 0; s < 2; ++s) {
          const bf16x8 kb = *(const bf16x8*)&Kl[1][sub * 16 + lcol][s * 32 + lgrp * 8];
          accs[4 + sub] = __builtin_amdgcn_mfma_f32_16x16x32_bf16(kb, s ? qf1 : qf0, accs[4 + sub], 0, 0, 0);
        }
      }
    } else {
#pragma unroll
      for (int sub = 4; sub < 8; ++sub) accs[sub] = f32x4{-1e30f, -1e30f, -1e30f, -1e30f};
    }
    __builtin_amdgcn_s_setprio(0);

    // causal mask (diagonal round only); Q already carries the 1/sqrt(D) scale
    if (diag) {
#pragma unroll
      for (int sub = 0; sub < 8; ++sub) {
        const int kvg = kv0 + sub * 16 + lgrp * 4;
#pragma unroll
        for (int r = 0; r < 4; ++r)
          if (kvg + r > q_l) accs[sub][r] = -1e30f;
      }
    }

    // in-register row max (31-op tree) + 2 shfl across the 4 lanes sharing this row
    float mx[8];
#pragma unroll
    for (int sub = 0; sub < 8; ++sub)
      mx[sub] = fmaxf(fmaxf(accs[sub][0], accs[sub][1]), fmaxf(accs[sub][2], accs[sub][3]));
    float rm = fmaxf(fmaxf(fmaxf(mx[0], mx[1]), fmaxf(mx[2], mx[3])),
                     fmaxf(fmaxf(mx[4], mx[5]), fmaxf(mx[6], mx[7])));
    rm = fmaxf(rm, __shfl_xor(rm, 16));
    rm = fmaxf(rm, __shfl_xor(rm, 32));
    const float nm = fmaxf(m1, rm);
    const float sf = __expf(m1 - nm);
    m1 = nm;

    // exp in place + row sum (tree) + 2 shfl
    float ps[8];
#pragma unroll
    for (int sub = 0; sub < 8; ++sub) {
#pragma unroll
      for (int r = 0; r < 4; ++r) accs[sub][r] = __expf(accs[sub][r] - nm);
      ps[sub] = (accs[sub][0] + accs[sub][1]) + (accs[sub][2] + accs[sub][3]);
    }
    float rs = ((ps[0] + ps[1]) + (ps[2] + ps[3])) + ((ps[4] + ps[5]) + (ps[6] + ps[7]));
    rs += __shfl_xor(rs, 16);
    rs += __shfl_xor(rs, 32);
    l1 = l1 * sf + rs;

    // rescale O^T by own-row sf
#pragma unroll
    for (int d = 0; d < 4; ++d)
#pragma unroll
      for (int r = 0; r < 4; ++r) acc_o[d][r] *= sf;

    // ---- PV half 0: P^T store (packed b64, swizzled) -> read A-frag -> MFMA ----
#pragma unroll
    for (int sub = 0; sub < 4; ++sub) {
      uint2 pk;
      pk.x = pack_bf16x2(accs[sub][0], accs[sub][1]);
      pk.y = pack_bf16x2(accs[sub][2], accs[sub][3]);
      const int eoff = ((((sub * 2 + (lgrp >> 1)) ^ ((lcol >> 2) & 3)) << 3) | ((lgrp & 1) << 2));
      *(uint2*)&Pl[w][lcol][eoff] = pk;
    }
    asm volatile("s_waitcnt lgkmcnt(0)" ::: "memory");
    __builtin_amdgcn_sched_barrier(0);  // rule 18
    __builtin_amdgcn_s_setprio(1);
#pragma unroll
    for (int s = 0; s < 2; ++s) {
      const bf16x8 pf = *(const bf16x8*)&Pl[w][lcol][((4 * s + lgrp) ^ ((lcol >> 2) & 3)) * 8];
#pragma unroll
      for (int d = 0; d < 4; ++d) {
        const bf16x8 vfr = *(const bf16x8*)&Vt[0][d * 16 + lcol][((4 * s + lgrp) ^ ((2 * d + (lcol >> 3)) & 7)) * 8];
        acc_o[d] = __builtin_amdgcn_mfma_f32_16x16x32_bf16(vfr, pf, acc_o[d], 0, 0, 0);
      }
    }
    __builtin_amdgcn_s_setprio(0);

    // ---- PV half 1 (skipped by waves 0-3 on the diagonal round) ----
    if (!skip1) {
#pragma unroll
      for (int sub = 0; sub < 4; ++sub) {
        uint2 pk;
        pk.x = pack_bf16x2(accs[4 + sub][0], accs[4 + sub][1]);
        pk.y = pack_bf16x2(accs[4 + sub][2], accs[4 + sub][3]);
        const int eoff = ((((sub * 2 + (lgrp >> 1)) ^ ((lcol >> 2) & 3)) << 3) | ((lgrp & 1) << 2));
        *(uint2*)&Pl[w][lcol][eoff] = pk;
      }
      asm volatile("s_waitcnt lgkmcnt(0)" ::: "memory");
      __builtin_amdgcn_sched_barrier(0);  // rule 18
      __builtin_amdgcn_s_setprio(1);
#pragma unroll
      for (int s = 0; s < 2; ++s) {
        const bf16x8 pf = *(const bf16x8*)&Pl[w][lcol][((4 * s + lgrp) ^ ((lcol >> 2) & 3)) * 8];
#pragma unroll
        for (int d = 0; d < 4; ++d) {
          const bf16x8 vfr = *(const bf16x8*)&Vt[1][d * 16 + lcol][((4 * s + lgrp) ^ ((2 * d + (lcol >> 3)) & 7)) * 8];
          acc_o[d] = __builtin_amdgcn_mfma_f32_16x16x32_bf16(vfr, pf, acc_o[d], 0, 0, 0);
        }
      }
      __builtin_amdgcn_s_setprio(0);
    }
  }

  // epilogue: O^T -> bf16 [B*T][1024]; lane owns q-row q_l, d = dsub*16+4*lgrp+{0..3}
  const float inv_l = 1.0f / l1;
  __bf16* orow = attnb + (size_t)(b * 2048 + q_l) * 1024 + h * 64 + lgrp * 4;
#pragma unroll
  for (int d = 0; d < 4; ++d) {
    uint2 ov;
    ov.x = pack_bf16x2(acc_o[d][0] * inv_l, acc_o[d][1] * inv_l);
    ov.y = pack_bf16x2(acc_o[d][2] * inv_l, acc_o[d][3] * inv_l);
    *(uint2*)(orow + d * 16) = ov;
  }
}

extern "C" void kernel_launch(void* const* d_in, const int* in_sizes, int n_in,
                              void* d_out, int out_size, void* d_ws, size_t ws_size,
                              hipStream_t stream) {
  const float* x    = (const float*)d_in[0];
  const float* Wqkv = (const float*)d_in[1];
  const float* bqkv = (const float*)d_in[2];
  const float* Wout = (const float*)d_in[3];
  const float* bout = (const float*)d_in[4];
  float* out = (float*)d_out;

  // Workspace plan (time-multiplexed):
  //   [0,24M)   qkvb  (bf16 [4096][3072])  -- dead after attn
  //   [24,30M)  wqkvT (bf16 [3072][1024])  -- dead after GEMM1
  //   [30,38M)  xb    (bf16 [4096][1024])  -- only if ws_size >= 38M
  //   [24,32M)  attnb (bf16 [4096][1024])  -- written by attn (over dead wqkvT)
  //   [0,2M)    woutT (bf16 [1024][1024])  -- transposed AFTER attn (over dead qkvb)
  char* ws = (char*)d_ws;
  __bf16* qkvb  = (__bf16*)(ws);
  __bf16* wqkvT = (__bf16*)(ws + (24u << 20));
  __bf16* xb    = (__bf16*)(ws + (30u << 20));
  __bf16* attnb = (__bf16*)(ws + (24u << 20));
  __bf16* woutT = (__bf16*)(ws);

  const bool big_ws = ws_size >= ((size_t)38 << 20);  // constant per process

  transpose_cast<<<dim3(3072 / 32, 1024 / 32), dim3(32, 8), 0, stream>>>(Wqkv, wqkvT, 1024, 3072);

  if (big_ws) {
    cvt_f32_to_bf16<<<dim3(4096 * 1024 / 2048), dim3(256), 0, stream>>>(x, xb, 4096 * 1024);
    gemm_bt<1, 0, 1><<<dim3(3072 / 128, 4096 / 128), dim3(256), 0, stream>>>(
        (const void*)xb, wqkvT, bqkv, (void*)qkvb, 4096, 3072, 1024);
  } else {
    gemm_bt<1, 1, 1><<<dim3(3072 / 128, 4096 / 128), dim3(256), 0, stream>>>(
        (const void*)x, wqkvT, bqkv, (void*)qkvb, 4096, 3072, 1024);
  }

  attn_fused<<<dim3(16, 2 * 16), dim3(512), 0, stream>>>(qkvb, attnb);

  transpose_cast<<<dim3(1024 / 32, 1024 / 32), dim3(32, 8), 0, stream>>>(Wout, woutT, 1024, 1024);

  gemm_bt<0, 0, 0><<<dim3(1024 / 128, 4096 / 128), dim3(256), 0, stream>>>(
      (const void*)attnb, woutT, bout, (void*)out, 4096, 1024, 1024);
}